// Round 5
// baseline (5050.601 us; speedup 1.0000x reference)
//
#include <hip/hip_runtime.h>
#include <cmath>
#include <cstdint>

// ---------------------------------------------------------------------------
// TransformerEncoderLayer (attention + MoE) on MI355X, fp32 acc.
// Round 5: per-kernel INLINE dtype detection (r4's shared dflag was clobbered
// by the alpha buffer at [11,13)MB -> all later kernels early-returned ->
// d_out stayed zero). Each dtype-templated kernel classifies d_in[0] itself.
// Corrected 16 MiB memory map: [11MB+256KB,12MB) is never touched.
// ---------------------------------------------------------------------------

typedef __bf16 bf16;
typedef __bf16 bf16x8 __attribute__((ext_vector_type(8)));
typedef float  f32x4  __attribute__((ext_vector_type(4)));

static constexpr int Bb = 2, Ss = 1024, Dd = 512, NHh = 8, HDd = 64;
static constexpr int Tt = Bb * Ss;           // 2048 tokens
static constexpr int NSs = 8, F3f = 1536;
static constexpr int Ee = 32, F2f = 1024;

// ---------------- helpers ----------------
__device__ inline float wavesum(float v) {
#pragma unroll
  for (int i = 1; i < 64; i <<= 1) v += __shfl_xor(v, i, 64);
  return v;
}
__device__ inline float blocksum(float v, float* sm) {
  v = wavesum(v);
  int wv = threadIdx.x >> 6;
  __syncthreads();
  if ((threadIdx.x & 63) == 0) sm[wv] = v;
  __syncthreads();
  return (sm[0] + sm[1]) + (sm[2] + sm[3]);
}
__device__ inline float silu_f(float x) { return x / (1.f + expf(-x)); }
__device__ inline float sigm_f(float x) { return 1.f / (1.f + expf(-x)); }

// Inline dtype classifier on d_in[0] (x ~ N(0,1)). Even uint16 elements:
// bf16 buffer -> real bf16 values, exponent almost surely in [110,140];
// fp32 buffer -> low halves of floats, exponent field = mantissa bits
// (~12% in range). Returns 1 if fp32. Deterministic across all blocks.
__device__ inline int is_f32(const unsigned short* __restrict__ xr) {
  int good = 0;
#pragma unroll
  for (int i = 0; i < 32; ++i) {
    unsigned e = (xr[2 * i] >> 7) & 0xFF;
    good += (e >= 110 && e <= 140);
  }
  return good < 16;
}

// load 8 contiguous elements as float
__device__ inline void ld8(const bf16* p, float* d) {
  bf16x8 v = *(const bf16x8*)p;
#pragma unroll
  for (int j = 0; j < 8; ++j) d[j] = (float)v[j];
}
__device__ inline void ld8(const float* p, float* d) {
  float4 a = *(const float4*)p;
  float4 b = *(const float4*)(p + 4);
  d[0] = a.x; d[1] = a.y; d[2] = a.z; d[3] = a.w;
  d[4] = b.x; d[5] = b.y; d[6] = b.z; d[7] = b.w;
}

// ---------------------------------------------------------------------------
// Flexible MFMA GEMM. C[M,N] = epilogue(scale * A[M,K] @ B[K,N] + bias).
// A is always ws bf16. B/bias/resid/ascale are TB (input dtype).
// Tile 64x64, BK=32, 4 waves. B element (k,n) at B[k*bK + n].
// DUAL: silu(A@B0)*(A@B1). ASCALE: A col k scaled by ascale[k].
// Fragment layouts (learn_hip m89/m91): A[m=lane&15][k=quad*8+j],
// B[k=quad*8+j][n=lane&15] from B^T tile, C row=quad*4+reg col=lane&15.
// ---------------------------------------------------------------------------
template <typename TB, int WANT, int ACT, int DUAL, int OUTBF, int ACCUM,
          int ROWW, int RESID, int ASCALE>
__global__ __launch_bounds__(256) void gemm_k(
    const unsigned short* __restrict__ xdet,
    const bf16* __restrict__ A, long aBatch, int lda,
    const TB* __restrict__ ascale,
    const TB* __restrict__ B0, const TB* __restrict__ B1, long bBatch, int bK,
    const TB* __restrict__ bias, int biasBatch,
    void* __restrict__ Cv, long cBatch, int ldc,
    const TB* __restrict__ resid, int resLd,
    const float* __restrict__ roww, int rowwStride,
    int N, int K, float scale) {
  if (is_f32(xdet) != WANT) return;
  __shared__ __align__(16) bf16 sA[64 * 40];
  __shared__ __align__(16) bf16 sB0[64 * 40];
  __shared__ __align__(16) bf16 sB1[64 * 40];

  const int tid = threadIdx.x;
  const int wave = tid >> 6, lane = tid & 63;
  const int fm = lane & 15, quad = lane >> 4;
  const int bm = blockIdx.x, bn = blockIdx.y, z = blockIdx.z;

  const bf16* Az = A + (long)z * aBatch;
  const TB* B0z = B0 + (long)z * bBatch;
  const TB* B1z = DUAL ? (B1 + (long)z * bBatch) : nullptr;

  f32x4 acc0[4], acc1[4];
  const f32x4 vzero = {0.f, 0.f, 0.f, 0.f};
#pragma unroll
  for (int i = 0; i < 4; ++i) { acc0[i] = vzero; acc1[i] = vzero; }

  const int arow = tid >> 2, ak0 = (tid & 3) * 8;          // A tile 64x32
  const int kk = tid >> 3, n0 = (tid & 7) * 8;             // B tile transpose

  for (int kb = 0; kb < K; kb += 32) {
    bf16x8 av = *(const bf16x8*)(Az + (long)(bm * 64 + arow) * lda + kb + ak0);
    if (ASCALE) {
#pragma unroll
      for (int j = 0; j < 8; ++j)
        av[j] = (bf16)((float)av[j] * (float)ascale[kb + ak0 + j]);
    }
    *(bf16x8*)(sA + arow * 40 + ak0) = av;
    int gn0 = bn * 64 + n0;
    if (gn0 < N) {
      float t0[8];
      ld8(B0z + (long)(kb + kk) * bK + gn0, t0);
#pragma unroll
      for (int j = 0; j < 8; ++j) sB0[(n0 + j) * 40 + kk] = (bf16)t0[j];
      if (DUAL) {
        float t1[8];
        ld8(B1z + (long)(kb + kk) * bK + gn0, t1);
#pragma unroll
        for (int j = 0; j < 8; ++j) sB1[(n0 + j) * 40 + kk] = (bf16)t1[j];
      }
    } else {
#pragma unroll
      for (int j = 0; j < 8; ++j) sB0[(n0 + j) * 40 + kk] = (bf16)0.f;
      if (DUAL) {
#pragma unroll
        for (int j = 0; j < 8; ++j) sB1[(n0 + j) * 40 + kk] = (bf16)0.f;
      }
    }
    __syncthreads();
    bf16x8 af = *(const bf16x8*)(sA + (wave * 16 + fm) * 40 + quad * 8);
#pragma unroll
    for (int nt = 0; nt < 4; ++nt) {
      bf16x8 bfr = *(const bf16x8*)(sB0 + (nt * 16 + fm) * 40 + quad * 8);
      acc0[nt] = __builtin_amdgcn_mfma_f32_16x16x32_bf16(af, bfr, acc0[nt], 0, 0, 0);
      if (DUAL) {
        bf16x8 bg = *(const bf16x8*)(sB1 + (nt * 16 + fm) * 40 + quad * 8);
        acc1[nt] = __builtin_amdgcn_mfma_f32_16x16x32_bf16(af, bg, acc1[nt], 0, 0, 0);
      }
    }
    __syncthreads();
  }

#pragma unroll
  for (int nt = 0; nt < 4; ++nt) {
    int gcol = bn * 64 + nt * 16 + fm;
    if (gcol >= N) continue;
#pragma unroll
    for (int r = 0; r < 4; ++r) {
      int grow = bm * 64 + wave * 16 + quad * 4 + r;
      float v;
      if (DUAL) {
        v = silu_f(acc0[nt][r]) * acc1[nt][r];
      } else {
        v = acc0[nt][r] * scale;
        if (bias) v += (float)bias[z * biasBatch + gcol];
        if (ACT == 1) v = silu_f(v);
        else if (ACT == 2) v = sigm_f(v);
      }
      if (ROWW) v *= roww[(long)grow * rowwStride];
      if (RESID) v += (float)resid[(long)grow * resLd + gcol];
      long ci = (long)z * cBatch + (long)grow * ldc + gcol;
      if (ACCUM) ((float*)Cv)[ci] += v;
      else if (OUTBF) ((bf16*)Cv)[ci] = (bf16)v;
      else ((float*)Cv)[ci] = v;
    }
  }
}

// ---------------------------------------------------------------------------
// Fused flash attention (all operands ws bf16 — no dtype dual needed).
// ---------------------------------------------------------------------------
__global__ __launch_bounds__(256) void attn_k(const bf16* __restrict__ Q,
                                              const bf16* __restrict__ K,
                                              const bf16* __restrict__ V,
                                              bf16* __restrict__ O) {
  __shared__ __align__(16) bf16 sK[64 * 72];
  __shared__ __align__(16) bf16 sVt[64 * 72];
  __shared__ __align__(16) bf16 sP[4 * 16 * 72];
  const int tid = threadIdx.x, wave = tid >> 6, lane = tid & 63;
  const int fm = lane & 15, quad = lane >> 4;
  const long base = (long)blockIdx.y * Ss * 64;
  const int qrow0 = blockIdx.x * 64 + wave * 16;

  bf16x8 qf[2];
#pragma unroll
  for (int c = 0; c < 2; ++c)
    qf[c] = *(const bf16x8*)(Q + base + (long)(qrow0 + fm) * 64 + c * 32 + quad * 8);

  f32x4 oacc[4];
  const f32x4 vz = {0.f, 0.f, 0.f, 0.f};
#pragma unroll
  for (int i = 0; i < 4; ++i) oacc[i] = vz;
  float m_run[4], l_run[4];
#pragma unroll
  for (int r = 0; r < 4; ++r) { m_run[r] = -1e30f; l_run[r] = 0.f; }

  const int skey = tid >> 2, sd0 = (tid & 3) * 16;
  const int vkey = tid >> 3, vd0 = (tid & 7) * 8;
  bf16* sPw = sP + wave * 16 * 72;

  for (int kt = 0; kt < 16; ++kt) {
    __syncthreads();
    const bf16* Kt = K + base + (long)(kt * 64) * 64;
    *(bf16x8*)(sK + skey * 72 + sd0)     = *(const bf16x8*)(Kt + (long)skey * 64 + sd0);
    *(bf16x8*)(sK + skey * 72 + sd0 + 8) = *(const bf16x8*)(Kt + (long)skey * 64 + sd0 + 8);
    const bf16* Vt = V + base + (long)(kt * 64) * 64;
#pragma unroll
    for (int h = 0; h < 2; ++h) {
      int key = vkey + h * 32;
      bf16x8 vv = *(const bf16x8*)(Vt + (long)key * 64 + vd0);
#pragma unroll
      for (int j = 0; j < 8; ++j) sVt[(vd0 + j) * 72 + key] = vv[j];
    }
    __syncthreads();
    f32x4 sacc[4];
#pragma unroll
    for (int nt = 0; nt < 4; ++nt) sacc[nt] = vz;
#pragma unroll
    for (int c = 0; c < 2; ++c) {
#pragma unroll
      for (int nt = 0; nt < 4; ++nt) {
        bf16x8 kf = *(const bf16x8*)(sK + (nt * 16 + fm) * 72 + c * 32 + quad * 8);
        sacc[nt] = __builtin_amdgcn_mfma_f32_16x16x32_bf16(qf[c], kf, sacc[nt], 0, 0, 0);
      }
    }
#pragma unroll
    for (int nt = 0; nt < 4; ++nt)
#pragma unroll
      for (int r = 0; r < 4; ++r) sacc[nt][r] *= 0.125f;
    float mt[4];
#pragma unroll
    for (int r = 0; r < 4; ++r) {
      float mx = -1e30f;
#pragma unroll
      for (int nt = 0; nt < 4; ++nt) mx = fmaxf(mx, sacc[nt][r]);
      mt[r] = mx;
    }
#pragma unroll
    for (int i = 1; i < 16; i <<= 1) {
#pragma unroll
      for (int r = 0; r < 4; ++r) mt[r] = fmaxf(mt[r], __shfl_xor(mt[r], i, 64));
    }
    float p[4][4], al[4], rs[4];
#pragma unroll
    for (int r = 0; r < 4; ++r) {
      float m_new = fmaxf(m_run[r], mt[r]);
      al[r] = expf(m_run[r] - m_new);
      m_run[r] = m_new;
      float s = 0.f;
#pragma unroll
      for (int nt = 0; nt < 4; ++nt) {
        float e = expf(sacc[nt][r] - m_new);
        p[nt][r] = e; s += e;
      }
      rs[r] = s;
    }
#pragma unroll
    for (int i = 1; i < 16; i <<= 1) {
#pragma unroll
      for (int r = 0; r < 4; ++r) rs[r] += __shfl_xor(rs[r], i, 64);
    }
#pragma unroll
    for (int r = 0; r < 4; ++r) l_run[r] = l_run[r] * al[r] + rs[r];
#pragma unroll
    for (int nt = 0; nt < 4; ++nt)
#pragma unroll
      for (int r = 0; r < 4; ++r) oacc[nt][r] *= al[r];
#pragma unroll
    for (int nt = 0; nt < 4; ++nt)
#pragma unroll
      for (int r = 0; r < 4; ++r)
        sPw[(quad * 4 + r) * 72 + nt * 16 + fm] = (bf16)p[nt][r];
    __syncthreads();
#pragma unroll
    for (int c = 0; c < 2; ++c) {
      bf16x8 pa = *(const bf16x8*)(sPw + fm * 72 + c * 32 + quad * 8);
#pragma unroll
      for (int nt = 0; nt < 4; ++nt) {
        bf16x8 vf = *(const bf16x8*)(sVt + (nt * 16 + fm) * 72 + c * 32 + quad * 8);
        oacc[nt] = __builtin_amdgcn_mfma_f32_16x16x32_bf16(pa, vf, oacc[nt], 0, 0, 0);
      }
    }
  }
#pragma unroll
  for (int nt = 0; nt < 4; ++nt) {
    int col = nt * 16 + fm;
#pragma unroll
    for (int r = 0; r < 4; ++r) {
      int row = qrow0 + quad * 4 + r;
      O[base + (long)row * 64 + col] = (bf16)(oacc[nt][r] / l_run[r]);
    }
  }
}

// ---------------- LayerNorm (D=512) -> bf16 ---------------------------------
template <typename TX, typename TW, int WANT>
__global__ __launch_bounds__(256) void ln_k(const unsigned short* __restrict__ xdet,
                                            const TX* __restrict__ xi,
                                            const TW* __restrict__ w,
                                            const TW* __restrict__ b,
                                            bf16* __restrict__ obf, float eps) {
  if (is_f32(xdet) != WANT) return;
  __shared__ float sm[4];
  long base = (long)blockIdx.x * 512;
  int tid = threadIdx.x;
  float x0 = (float)xi[base + tid], x1 = (float)xi[base + 256 + tid];
  float mean = blocksum(x0 + x1, sm) * (1.f / 512.f);
  float d0 = x0 - mean, d1 = x1 - mean;
  float var = blocksum(d0 * d0 + d1 * d1, sm) * (1.f / 512.f);
  float r = rsqrtf(var + eps);
  obf[base + tid] = (bf16)(d0 * r * (float)w[tid] + (float)b[tid]);
  obf[base + 256 + tid] = (bf16)(d1 * r * (float)w[256 + tid] + (float)b[256 + tid]);
}

// ---------------- RMSNorm (bf16 in, eps 1e-6) -> bf16 -----------------------
__global__ __launch_bounds__(256) void rms_k(const bf16* __restrict__ xi,
                                             bf16* __restrict__ ob) {
  __shared__ float sm[4];
  long base = (long)blockIdx.x * 512;
  int tid = threadIdx.x;
  float x0 = (float)xi[base + tid], x1 = (float)xi[base + 256 + tid];
  float ms = blocksum(x0 * x0 + x1 * x1, sm) * (1.f / 512.f);
  float r = rsqrtf(ms + 1e-6f);
  ob[base + tid] = (bf16)(x0 * r);
  ob[base + 256 + tid] = (bf16)(x1 * r);
}

// ---- q/k l2norm (in place) + v = v*alpha+beta (in place), 1 wave / row -----
__global__ __launch_bounds__(256) void postproj_k(
    bf16* __restrict__ q, bf16* __restrict__ k, bf16* __restrict__ v,
    const bf16* __restrict__ al, const bf16* __restrict__ be) {
  int wv = threadIdx.x >> 6, lane = threadIdx.x & 63;
  long i = ((long)blockIdx.x * 4 + wv) * 64 + lane;
  float qv = (float)q[i];
  float nq = sqrtf(wavesum(qv * qv));
  q[i] = (bf16)(qv / fmaxf(nq, 1e-12f));
  float kv = (float)k[i];
  float nk = sqrtf(wavesum(kv * kv));
  k[i] = (bf16)(kv / fmaxf(nk, 1e-12f));
  v[i] = (bf16)((float)v[i] * (float)al[i] + (float)be[i]);
}

// ---- o = rms(o)*arms_w*shortcut, in place ----------------------------------
template <typename T, int WANT>
__global__ __launch_bounds__(256) void orms_k(const unsigned short* __restrict__ xdet,
                                              bf16* __restrict__ o,
                                              const T* __restrict__ arms,
                                              const bf16* __restrict__ sc) {
  if (is_f32(xdet) != WANT) return;
  int wv = threadIdx.x >> 6, lane = threadIdx.x & 63;
  long r = (long)blockIdx.x * 4 + wv;
  long i = r * 64 + lane;
  int h = (int)(r >> 11);
  float ov = (float)o[i];
  float ms = wavesum(ov * ov) * (1.f / 64.f);
  float s = rsqrtf(ms + 1e-6f);
  o[i] = (bf16)(ov * s * (float)arms[h * 64 + lane] * (float)sc[i]);
}

// ---------------- router: fp32 LN inside, logits, top-4, counts -------------
template <typename T, int WANT>
__global__ __launch_bounds__(256) void router_k(const unsigned short* __restrict__ xdet,
                                                const float* __restrict__ x2,
                                                const T* __restrict__ lnw,
                                                const T* __restrict__ lnb,
                                                const T* __restrict__ rdw,
                                                const T* __restrict__ ruw,
                                                float* __restrict__ wfull,
                                                float* __restrict__ counts) {
  if (is_f32(xdet) != WANT) return;
  __shared__ float sx[4][512];
  __shared__ float st[4][64];
  __shared__ float sl[4][32];
  int wv = threadIdx.x >> 6, lane = threadIdx.x & 63;
  long t = (long)blockIdx.x * 4 + wv;
  float v[8];
  float s1 = 0.f;
#pragma unroll
  for (int j = 0; j < 8; ++j) { v[j] = x2[t * 512 + lane * 8 + j]; s1 += v[j]; }
  float mean = wavesum(s1) * (1.f / 512.f);
  float s2 = 0.f;
#pragma unroll
  for (int j = 0; j < 8; ++j) { float d = v[j] - mean; s2 += d * d; }
  float rv = rsqrtf(wavesum(s2) * (1.f / 512.f) + 1e-5f);
#pragma unroll
  for (int j = 0; j < 8; ++j)
    sx[wv][lane * 8 + j] = (v[j] - mean) * rv * (float)lnw[lane * 8 + j] + (float)lnb[lane * 8 + j];
  __syncthreads();
  float acc = 0.f;
  for (int d = 0; d < 512; ++d) acc += sx[wv][d] * (float)rdw[d * 64 + lane];
  st[wv][lane] = acc;
  __syncthreads();
  if (lane < 32) {
    float lg = 0.f;
    for (int r = 0; r < 64; ++r) lg += st[wv][r] * (float)ruw[r * 32 + lane];
    sl[wv][lane] = lg;
  }
  __syncthreads();
  if (lane == 0) {
    float vv[32];
#pragma unroll
    for (int e = 0; e < 32; ++e) vv[e] = sl[wv][e];
    int idx[4]; float tv[4];
#pragma unroll
    for (int k = 0; k < 4; ++k) {
      float best = -1e30f; int bi = 0;
      for (int e = 0; e < 32; ++e)
        if (vv[e] > best) { best = vv[e]; bi = e; }
      tv[k] = best; idx[k] = bi; vv[bi] = -1e30f;
    }
    float m = tv[0], s = 0.f, w[4];
#pragma unroll
    for (int k = 0; k < 4; ++k) { w[k] = expf(tv[k] - m); s += w[k]; }
    float inv = 1.f / s;
#pragma unroll
    for (int k = 0; k < 4; ++k) {
      wfull[t * 32 + idx[k]] = w[k] * inv;
      atomicAdd(&counts[idx[k]], 1.0f);
    }
  }
}

// ---------------- misc ----------------
__global__ void zero_k(float* __restrict__ p, long n) {
  long i = (long)blockIdx.x * blockDim.x + threadIdx.x;
  long st = (long)gridDim.x * blockDim.x;
  for (; i < n; i += st) p[i] = 0.f;
}
// out = x2 + ln2(x2) + acc
template <typename TW, typename TO, int WANT>
__global__ __launch_bounds__(256) void final_k(const unsigned short* __restrict__ xdet,
                                               const float* __restrict__ x2,
                                               const TW* __restrict__ lnw,
                                               const TW* __restrict__ lnb,
                                               const float* __restrict__ acc,
                                               TO* __restrict__ out) {
  if (is_f32(xdet) != WANT) return;
  __shared__ float sm[4];
  long base = (long)blockIdx.x * 512;
  int tid = threadIdx.x;
  float x0 = x2[base + tid], x1 = x2[base + 256 + tid];
  float mean = blocksum(x0 + x1, sm) * (1.f / 512.f);
  float d0 = x0 - mean, d1 = x1 - mean;
  float var = blocksum(d0 * d0 + d1 * d1, sm) * (1.f / 512.f);
  float r = rsqrtf(var + 1e-5f);
  float f0 = d0 * r * (float)lnw[tid] + (float)lnb[tid];
  float f1 = d1 * r * (float)lnw[256 + tid] + (float)lnb[256 + tid];
  out[base + tid] = (TO)(x0 + f0 + acc[base + tid]);
  out[base + 256 + tid] = (TO)(x1 + f1 + acc[base + 256 + tid]);
}
template <typename TO, int WANT>
__global__ void loss_k(const unsigned short* __restrict__ xdet,
                       const float* __restrict__ counts, TO* __restrict__ out) {
  if (is_f32(xdet) != WANT) return;
  int lane = threadIdx.x;
  float c = lane < 32 ? counts[lane] : 0.f;
  float mean = wavesum(c) * (1.f / 32.f);
  float d = lane < 32 ? (c - mean) * (c - mean) : 0.f;
  float var = wavesum(d) * (1.f / 31.f);
  if (lane == 0) out[(long)Tt * 512] = (TO)var;
}

// ---------------- host-side dual-dispatch helper for gemm_k -----------------
template <int ACT, int DUAL, int OUTBF, int ACCUM, int ROWW, int RESID, int ASCALE>
static inline void G(dim3 grid, hipStream_t st, const unsigned short* xdet,
                     const bf16* A, long aB, int lda,
                     const void* ascale, long asOff,
                     const void* B0, long b0Off, const void* B1, long b1Off,
                     long bB, int bK,
                     const void* bias, int biasB,
                     void* C, long cB, int ldc,
                     const void* resid, int resLd,
                     const float* roww, int rwS, int N, int K, float scale) {
  gemm_k<float, 1, ACT, DUAL, OUTBF, ACCUM, ROWW, RESID, ASCALE><<<grid, 256, 0, st>>>(
      xdet, A, aB, lda,
      ascale ? (const float*)ascale + asOff : nullptr,
      (const float*)B0 + b0Off, B1 ? (const float*)B1 + b1Off : nullptr, bB, bK,
      bias ? (const float*)bias : nullptr, biasB, C, cB, ldc,
      resid ? (const float*)resid : nullptr, resLd, roww, rwS, N, K, scale);
  gemm_k<bf16, 0, ACT, DUAL, OUTBF, ACCUM, ROWW, RESID, ASCALE><<<grid, 256, 0, st>>>(
      xdet, A, aB, lda,
      ascale ? (const bf16*)ascale + asOff : nullptr,
      (const bf16*)B0 + b0Off, B1 ? (const bf16*)B1 + b1Off : nullptr, bB, bK,
      bias ? (const bf16*)bias : nullptr, biasB, C, cB, ldc,
      resid ? (const bf16*)resid : nullptr, resLd, roww, rwS, N, K, scale);
}

// ---------------------------------------------------------------------------
extern "C" void kernel_launch(void* const* d_in, const int* in_sizes, int n_in,
                              void* d_out, int out_size, void* d_ws, size_t ws_size,
                              hipStream_t stream) {
  (void)in_sizes; (void)n_in; (void)out_size; (void)ws_size;
  const void* x    = d_in[0];
  const void* ln1w = d_in[1];
  const void* ln1b = d_in[2];
  const void* ln2w = d_in[3];
  const void* ln2b = d_in[4];
  const void* q_w  = d_in[5];
  const void* q_b  = d_in[6];
  const void* k_w  = d_in[7];
  const void* k_b  = d_in[8];
  const void* v_w  = d_in[9];
  const void* v_b  = d_in[10];
  const void* aw1  = d_in[11];
  const void* ab1  = d_in[12];
  const void* aw2  = d_in[13];
  const void* ab2  = d_in[14];
  const void* bw   = d_in[15];
  const void* bbv  = d_in[16];
  const void* scw1 = d_in[17];
  const void* scb1 = d_in[18];
  const void* scw2 = d_in[19];
  const void* scb2 = d_in[20];
  const void* arms = d_in[21];
  const void* l1w  = d_in[22];
  const void* l1b  = d_in[23];
  const void* outw = d_in[24];
  const void* outb = d_in[25];
  const void* shrms= d_in[26];
  const void* shw1 = d_in[27];
  const void* shw2 = d_in[28];
  const void* shw3 = d_in[29];
  const void* rw1  = d_in[30];
  const void* rw2  = d_in[31];
  const void* rw3  = d_in[32];
  const void* rdw  = d_in[33];
  const void* ruw  = d_in[34];
  const unsigned short* xdet = (const unsigned short*)x;

  // ---- workspace map: PEAK 16 MiB, phase-overlaid.
  // Attention: xn[0,2) qh[2,4) kh[4,6) vh[6,8) beta[8,10) ah[10,11)
  //            alpha[12,14) | sch[8,9) shct[14,16) | oatt[8,10)
  //            conc[2,4) x2[4,8)fp32
  // MoE:       xfb[0,2) rbb[2,4) gv[8,11) wfull[11MB,+256KB)+counts
  //            acc[12,16)fp32.   [11MB+264KB, 12MB) never touched.
  constexpr size_t MB = 1u << 20;
  char* base = (char*)d_ws;
  bf16* xn    = (bf16*)(base + 0 * MB);
  bf16* qh    = (bf16*)(base + 2 * MB);
  bf16* kh    = (bf16*)(base + 4 * MB);
  bf16* vh    = (bf16*)(base + 6 * MB);
  bf16* beta  = (bf16*)(base + 8 * MB);
  bf16* ah    = (bf16*)(base + 10 * MB);
  bf16* alpha = (bf16*)(base + 12 * MB);
  bf16* sch   = (bf16*)(base + 8 * MB);
  bf16* shct  = (bf16*)(base + 14 * MB);
  bf16* oatt  = (bf16*)(base + 8 * MB);
  bf16* conc  = (bf16*)(base + 2 * MB);
  float* x2   = (float*)(base + 4 * MB);
  bf16* xfb   = (bf16*)(base + 0 * MB);
  bf16* rbb   = (bf16*)(base + 2 * MB);
  bf16* gv    = (bf16*)(base + 8 * MB);
  float* wfull= (float*)(base + 11 * MB);
  float* counts = wfull + (long)Tt * 32;
  float* acc  = (float*)(base + 12 * MB);

  // ---- attention sublayer ----
  ln_k<float, float, 1><<<Tt, 256, 0, stream>>>(xdet, (const float*)x, (const float*)ln1w, (const float*)ln1b, xn, 1e-5f);
  ln_k<bf16, bf16, 0><<<Tt, 256, 0, stream>>>(xdet, (const bf16*)x, (const bf16*)ln1w, (const bf16*)ln1b, xn, 1e-5f);

  G<1,0,1,0,0,0,0>(dim3(32,1,8), stream, xdet, xn,0,512, nullptr,0, q_w,0,nullptr,0,(long)512*64,64, q_b,64, qh,(long)Tt*64,64, nullptr,0, nullptr,0, 64,512,1.f);
  G<1,0,1,0,0,0,0>(dim3(32,1,8), stream, xdet, xn,0,512, nullptr,0, k_w,0,nullptr,0,(long)512*64,64, k_b,64, kh,(long)Tt*64,64, nullptr,0, nullptr,0, 64,512,1.f);
  G<1,0,1,0,0,0,0>(dim3(32,1,8), stream, xdet, xn,0,512, nullptr,0, v_w,0,nullptr,0,(long)512*64,64, v_b,64, vh,(long)Tt*64,64, nullptr,0, nullptr,0, 64,512,1.f);
  G<2,0,1,0,0,0,0>(dim3(32,1,8), stream, xdet, xn,0,512, nullptr,0, bw,0,nullptr,0,(long)512*64,64, bbv,64, beta,(long)Tt*64,64, nullptr,0, nullptr,0, 64,512,1.f);
  G<0,0,1,0,0,0,0>(dim3(32,1,8), stream, xdet, xn,0,512, nullptr,0, aw1,0,nullptr,0,(long)512*32,32, ab1,32, ah,(long)Tt*32,32, nullptr,0, nullptr,0, 32,512,1.f);
  G<2,0,1,0,0,0,0>(dim3(32,1,8), stream, xdet, ah,(long)Tt*32,32, nullptr,0, aw2,0,nullptr,0,(long)32*64,64, ab2,64, alpha,(long)Tt*64,64, nullptr,0, nullptr,0, 64,32,1.f);

  postproj_k<<<NHh * Tt / 4, 256, 0, stream>>>(qh, kh, vh, alpha, beta);

  G<0,0,1,0,0,0,0>(dim3(32,1,8), stream, xdet, xn,0,512, nullptr,0, scw1,0,nullptr,0,(long)512*32,32, scb1,32, sch,(long)Tt*32,32, nullptr,0, nullptr,0, 32,512,1.f);
  G<2,0,1,0,0,0,0>(dim3(32,1,8), stream, xdet, sch,(long)Tt*32,32, nullptr,0, scw2,0,nullptr,0,(long)32*64,64, scb2,64, shct,(long)Tt*64,64, nullptr,0, nullptr,0, 64,32,1.f);

  attn_k<<<dim3(16, 16), 256, 0, stream>>>(qh, kh, vh, oatt);

  orms_k<float, 1><<<NHh * Tt / 4, 256, 0, stream>>>(xdet, oatt, (const float*)arms, shct);
  orms_k<bf16, 0><<<NHh * Tt / 4, 256, 0, stream>>>(xdet, oatt, (const bf16*)arms, shct);

  G<0,0,1,0,0,0,0>(dim3(32,1,8), stream, xdet, oatt,(long)Tt*64,64, nullptr,0, l1w,0,nullptr,0,(long)64*64,64, l1b,64, conc,64,512, nullptr,0, nullptr,0, 64,64,1.f);
  G<0,0,0,0,0,1,0>(dim3(32,8,1), stream, xdet, conc,0,512, nullptr,0, outw,0,nullptr,0,0,512, outb,0, x2,0,512, x,512, nullptr,0, 512,512,1.f);

  // ---- MoE sublayer ----
  ln_k<float, float, 1><<<Tt, 256, 0, stream>>>(xdet, x2, (const float*)ln2w, (const float*)ln2b, xfb, 1e-5f);
  ln_k<float, bf16, 0><<<Tt, 256, 0, stream>>>(xdet, x2, (const bf16*)ln2w, (const bf16*)ln2b, xfb, 1e-5f);
  rms_k<<<Tt, 256, 0, stream>>>(xfb, rbb);
  zero_k<<<256, 256, 0, stream>>>(acc, (long)Tt * 512);
  zero_k<<<64, 256, 0, stream>>>(wfull, (long)Tt * 32 + 64);
  router_k<float, 1><<<Tt / 4, 256, 0, stream>>>(xdet, x2, (const float*)ln2w, (const float*)ln2b, (const float*)rdw, (const float*)ruw, wfull, counts);
  router_k<bf16, 0><<<Tt / 4, 256, 0, stream>>>(xdet, x2, (const bf16*)ln2w, (const bf16*)ln2b, (const bf16*)rdw, (const bf16*)ruw, wfull, counts);

  // shared experts, column-halved (hidden half 768 cols = 3MB at [8,11))
  for (int n = 0; n < NSs; ++n) {
    for (int h = 0; h < 2; ++h) {
      G<0,1,1,0,0,0,1>(dim3(32,12,1), stream, xdet, rbb,0,512, shrms,(long)n*512,
                       shw1,(long)n*512*F3f + h*768, shw3,(long)n*512*F3f + h*768, 0,F3f,
                       nullptr,0, gv,0,768, nullptr,0, nullptr,0, 768,512,1.f);
      G<0,0,0,1,0,0,0>(dim3(32,8,1), stream, xdet, gv,0,768, nullptr,0,
                       shw2,(long)n*F3f*512 + (long)h*768*512, nullptr,0, 0,512,
                       nullptr,0, acc,0,512, nullptr,0, nullptr,0, 512,768,0.125f);
    }
  }

  // routed experts (dense, masked combine via per-row weight), column-halved
  for (int e = 0; e < Ee; ++e) {
    for (int h = 0; h < 2; ++h) {
      G<0,1,1,0,0,0,0>(dim3(32,8,1), stream, xdet, xfb,0,512, nullptr,0,
                       rw1,(long)e*512*F2f + h*512, rw3,(long)e*512*F2f + h*512, 0,F2f,
                       nullptr,0, gv,0,512, nullptr,0, nullptr,0, 512,512,1.f);
      G<0,0,0,1,1,0,0>(dim3(32,8,1), stream, xdet, gv,0,512, nullptr,0,
                       rw2,(long)e*F2f*512 + (long)h*512*512, nullptr,0, 0,512,
                       nullptr,0, acc,0,512, nullptr,0, wfull+e,32, 512,512,1.f);
    }
  }

  final_k<float, float, 1><<<Tt, 256, 0, stream>>>(xdet, x2, (const float*)ln2w, (const float*)ln2b, acc, (float*)d_out);
  final_k<bf16, bf16, 0><<<Tt, 256, 0, stream>>>(xdet, x2, (const bf16*)ln2w, (const bf16*)ln2b, acc, (bf16*)d_out);
  loss_k<float, 1><<<1, 64, 0, stream>>>(xdet, counts, (float*)d_out);
  loss_k<bf16, 0><<<1, 64, 0, stream>>>(xdet, counts, (bf16*)d_out);
}

// Round 7
// 1340.194 us; speedup vs baseline: 3.7686x; 3.7686x over previous
//
#include <hip/hip_runtime.h>
#include <cmath>
#include <cstdint>

// ---------------------------------------------------------------------------
// TransformerEncoderLayer (attention + MoE) on MI355X, fp32 acc.
// Round 7 (= round 6 resubmit after GPU-broker timeout): sparse token-gathered
// routed experts (206->~32 GF) + launch-count collapse + ws_size-adaptive
// hidden buffer. Keeps r5's proven inline fp32/bf16 dtype detection and dual
// dispatch, and r5's attention phase.
// ---------------------------------------------------------------------------

typedef __bf16 bf16;
typedef __bf16 bf16x8 __attribute__((ext_vector_type(8)));
typedef float  f32x4  __attribute__((ext_vector_type(4)));

static constexpr int Bb = 2, Ss = 1024, Dd = 512, NHh = 8, HDd = 64;
static constexpr int Tt = Bb * Ss;           // 2048 tokens
static constexpr int NSs = 8, F3f = 1536;
static constexpr int Ee = 32, F2f = 1024;
static constexpr int SLOTCAP = 10240;        // 8192 + worst-case pad (10208)
static constexpr int MAXTILE = 160;

// ---------------- helpers ----------------
__device__ inline float wavesum(float v) {
#pragma unroll
  for (int i = 1; i < 64; i <<= 1) v += __shfl_xor(v, i, 64);
  return v;
}
__device__ inline float blocksum(float v, float* sm) {
  v = wavesum(v);
  int wv = threadIdx.x >> 6;
  __syncthreads();
  if ((threadIdx.x & 63) == 0) sm[wv] = v;
  __syncthreads();
  return (sm[0] + sm[1]) + (sm[2] + sm[3]);
}
__device__ inline float silu_f(float x) { return x / (1.f + expf(-x)); }
__device__ inline float sigm_f(float x) { return 1.f / (1.f + expf(-x)); }

// Inline dtype classifier on d_in[0] (x ~ N(0,1)); 1 = fp32 buffer.
__device__ inline int is_f32(const unsigned short* __restrict__ xr) {
  int good = 0;
#pragma unroll
  for (int i = 0; i < 32; ++i) {
    unsigned e = (xr[2 * i] >> 7) & 0xFF;
    good += (e >= 110 && e <= 140);
  }
  return good < 16;
}

__device__ inline void ld8(const bf16* p, float* d) {
  bf16x8 v = *(const bf16x8*)p;
#pragma unroll
  for (int j = 0; j < 8; ++j) d[j] = (float)v[j];
}
__device__ inline void ld8(const float* p, float* d) {
  float4 a = *(const float4*)p;
  float4 b = *(const float4*)(p + 4);
  d[0] = a.x; d[1] = a.y; d[2] = a.z; d[3] = a.w;
  d[4] = b.x; d[5] = b.y; d[6] = b.z; d[7] = b.w;
}

// ---------------------------------------------------------------------------
// Flexible MFMA GEMM (ACCUM = atomicAdd so z-batching is safe).
// Fragment layouts (learn_hip m89/m91): A[m=lane&15][k=quad*8+j],
// B[k=quad*8+j][n=lane&15] from B^T tile, C row=quad*4+reg col=lane&15.
// ---------------------------------------------------------------------------
template <typename TB, int WANT, int ACT, int DUAL, int OUTBF, int ACCUM,
          int RESID, int ASCALE>
__global__ __launch_bounds__(256) void gemm_k(
    const unsigned short* __restrict__ xdet,
    const bf16* __restrict__ A, long aBatch, int lda,
    const TB* __restrict__ ascale, long asBatch,
    const TB* __restrict__ B0, const TB* __restrict__ B1, long bBatch, int bK,
    const TB* __restrict__ bias, int biasBatch,
    void* __restrict__ Cv, long cBatch, int ldc,
    const TB* __restrict__ resid, int resLd,
    int N, int K, float scale) {
  if (is_f32(xdet) != WANT) return;
  __shared__ __align__(16) bf16 sA[64 * 40];
  __shared__ __align__(16) bf16 sB0[64 * 40];
  __shared__ __align__(16) bf16 sB1[64 * 40];

  const int tid = threadIdx.x;
  const int wave = tid >> 6, lane = tid & 63;
  const int fm = lane & 15, quad = lane >> 4;
  const int bm = blockIdx.x, bn = blockIdx.y, z = blockIdx.z;

  const bf16* Az = A + (long)z * aBatch;
  const TB* B0z = B0 + (long)z * bBatch;
  const TB* B1z = DUAL ? (B1 + (long)z * bBatch) : nullptr;
  const TB* asz = ASCALE ? (ascale + (long)z * asBatch) : nullptr;

  f32x4 acc0[4], acc1[4];
  const f32x4 vzero = {0.f, 0.f, 0.f, 0.f};
#pragma unroll
  for (int i = 0; i < 4; ++i) { acc0[i] = vzero; acc1[i] = vzero; }

  const int arow = tid >> 2, ak0 = (tid & 3) * 8;
  const int kk = tid >> 3, n0 = (tid & 7) * 8;

  for (int kb = 0; kb < K; kb += 32) {
    bf16x8 av = *(const bf16x8*)(Az + (long)(bm * 64 + arow) * lda + kb + ak0);
    if (ASCALE) {
#pragma unroll
      for (int j = 0; j < 8; ++j)
        av[j] = (bf16)((float)av[j] * (float)asz[kb + ak0 + j]);
    }
    *(bf16x8*)(sA + arow * 40 + ak0) = av;
    int gn0 = bn * 64 + n0;
    if (gn0 < N) {
      float t0[8];
      ld8(B0z + (long)(kb + kk) * bK + gn0, t0);
#pragma unroll
      for (int j = 0; j < 8; ++j) sB0[(n0 + j) * 40 + kk] = (bf16)t0[j];
      if (DUAL) {
        float t1[8];
        ld8(B1z + (long)(kb + kk) * bK + gn0, t1);
#pragma unroll
        for (int j = 0; j < 8; ++j) sB1[(n0 + j) * 40 + kk] = (bf16)t1[j];
      }
    } else {
#pragma unroll
      for (int j = 0; j < 8; ++j) sB0[(n0 + j) * 40 + kk] = (bf16)0.f;
      if (DUAL) {
#pragma unroll
        for (int j = 0; j < 8; ++j) sB1[(n0 + j) * 40 + kk] = (bf16)0.f;
      }
    }
    __syncthreads();
    bf16x8 af = *(const bf16x8*)(sA + (wave * 16 + fm) * 40 + quad * 8);
#pragma unroll
    for (int nt = 0; nt < 4; ++nt) {
      bf16x8 bfr = *(const bf16x8*)(sB0 + (nt * 16 + fm) * 40 + quad * 8);
      acc0[nt] = __builtin_amdgcn_mfma_f32_16x16x32_bf16(af, bfr, acc0[nt], 0, 0, 0);
      if (DUAL) {
        bf16x8 bg = *(const bf16x8*)(sB1 + (nt * 16 + fm) * 40 + quad * 8);
        acc1[nt] = __builtin_amdgcn_mfma_f32_16x16x32_bf16(af, bg, acc1[nt], 0, 0, 0);
      }
    }
    __syncthreads();
  }

#pragma unroll
  for (int nt = 0; nt < 4; ++nt) {
    int gcol = bn * 64 + nt * 16 + fm;
    if (gcol >= N) continue;
#pragma unroll
    for (int r = 0; r < 4; ++r) {
      int grow = bm * 64 + wave * 16 + quad * 4 + r;
      float v;
      if (DUAL) {
        v = silu_f(acc0[nt][r]) * acc1[nt][r];
      } else {
        v = acc0[nt][r] * scale;
        if (bias) v += (float)bias[z * biasBatch + gcol];
        if (ACT == 1) v = silu_f(v);
        else if (ACT == 2) v = sigm_f(v);
      }
      if (RESID) v += (float)resid[(long)grow * resLd + gcol];
      long ci = (long)z * cBatch + (long)grow * ldc + gcol;
      if (ACCUM) atomicAdd((float*)Cv + ci, v);
      else if (OUTBF) ((bf16*)Cv)[ci] = (bf16)v;
      else ((float*)Cv)[ci] = v;
    }
  }
}

// ---------------------------------------------------------------------------
// Sparse routed expert stage 1: gathered dual-SwiGLU GEMM into hidden buffer.
// ---------------------------------------------------------------------------
template <typename TB, int WANT>
__global__ __launch_bounds__(256) void moe1_k(
    const unsigned short* __restrict__ xdet,
    const int* __restrict__ tileExp, const int* __restrict__ tileStart,
    const int* __restrict__ slotTok,
    const bf16* __restrict__ xfb,
    const TB* __restrict__ W1, const TB* __restrict__ W3,
    bf16* __restrict__ hid, int Ps, int colOff, int Np) {
  if (is_f32(xdet) != WANT) return;
  int e = tileExp[blockIdx.x];
  if (e < 0) return;
  int slot0 = tileStart[blockIdx.x];
  __shared__ int sTok[64];
  __shared__ __align__(16) bf16 sA[64 * 40];
  __shared__ __align__(16) bf16 sB0[64 * 40];
  __shared__ __align__(16) bf16 sB1[64 * 40];
  const int tid = threadIdx.x;
  const int wave = tid >> 6, lane = tid & 63;
  const int fm = lane & 15, quad = lane >> 4;
  if (tid < 64) sTok[tid] = slotTok[slot0 + tid];
  __syncthreads();
  const TB* B0 = W1 + (long)e * 512 * F2f + colOff;
  const TB* B1 = W3 + (long)e * 512 * F2f + colOff;
  const int bn = blockIdx.y;
  f32x4 acc0[4], acc1[4];
  const f32x4 vz = {0.f, 0.f, 0.f, 0.f};
#pragma unroll
  for (int i = 0; i < 4; ++i) { acc0[i] = vz; acc1[i] = vz; }
  const int arow = tid >> 2, ak0 = (tid & 3) * 8;
  const int kk = tid >> 3, n0 = (tid & 7) * 8;
  for (int kb = 0; kb < 512; kb += 32) {
    int tok = sTok[arow];
    *(bf16x8*)(sA + arow * 40 + ak0) =
        *(const bf16x8*)(xfb + (long)tok * 512 + kb + ak0);
    int gn0 = bn * 64 + n0;
    if (gn0 < Np) {
      float t0[8], t1[8];
      ld8(B0 + (long)(kb + kk) * F2f + gn0, t0);
      ld8(B1 + (long)(kb + kk) * F2f + gn0, t1);
#pragma unroll
      for (int j = 0; j < 8; ++j) {
        sB0[(n0 + j) * 40 + kk] = (bf16)t0[j];
        sB1[(n0 + j) * 40 + kk] = (bf16)t1[j];
      }
    } else {
#pragma unroll
      for (int j = 0; j < 8; ++j) {
        sB0[(n0 + j) * 40 + kk] = (bf16)0.f;
        sB1[(n0 + j) * 40 + kk] = (bf16)0.f;
      }
    }
    __syncthreads();
    bf16x8 af = *(const bf16x8*)(sA + (wave * 16 + fm) * 40 + quad * 8);
#pragma unroll
    for (int nt = 0; nt < 4; ++nt) {
      bf16x8 bfr = *(const bf16x8*)(sB0 + (nt * 16 + fm) * 40 + quad * 8);
      acc0[nt] = __builtin_amdgcn_mfma_f32_16x16x32_bf16(af, bfr, acc0[nt], 0, 0, 0);
      bf16x8 bg = *(const bf16x8*)(sB1 + (nt * 16 + fm) * 40 + quad * 8);
      acc1[nt] = __builtin_amdgcn_mfma_f32_16x16x32_bf16(af, bg, acc1[nt], 0, 0, 0);
    }
    __syncthreads();
  }
#pragma unroll
  for (int nt = 0; nt < 4; ++nt) {
    int gcol = bn * 64 + nt * 16 + fm;
    if (gcol >= Np) continue;
#pragma unroll
    for (int r = 0; r < 4; ++r) {
      int row = wave * 16 + quad * 4 + r;
      hid[(long)(slot0 + row) * Ps + gcol] =
          (bf16)(silu_f(acc0[nt][r]) * acc1[nt][r]);
    }
  }
}

// ---------------------------------------------------------------------------
// Sparse routed expert stage 2: hidden @ W2, scatter-add w*out into acc.
// ---------------------------------------------------------------------------
template <typename TB, int WANT>
__global__ __launch_bounds__(256) void moe2_k(
    const unsigned short* __restrict__ xdet,
    const int* __restrict__ tileExp, const int* __restrict__ tileStart,
    const int* __restrict__ slotTok, const float* __restrict__ slotW,
    const bf16* __restrict__ hid, int Ps, int colOff, int Kp,
    const TB* __restrict__ W2, float* __restrict__ acc) {
  if (is_f32(xdet) != WANT) return;
  int e = tileExp[blockIdx.x];
  if (e < 0) return;
  int slot0 = tileStart[blockIdx.x];
  __shared__ int sTok[64];
  __shared__ float sW[64];
  __shared__ __align__(16) bf16 sA[64 * 40];
  __shared__ __align__(16) bf16 sB0[64 * 40];
  const int tid = threadIdx.x;
  const int wave = tid >> 6, lane = tid & 63;
  const int fm = lane & 15, quad = lane >> 4;
  if (tid < 64) { sTok[tid] = slotTok[slot0 + tid]; sW[tid] = slotW[slot0 + tid]; }
  __syncthreads();
  const TB* B0 = W2 + (long)e * F2f * 512 + (long)colOff * 512;
  const int bn = blockIdx.y;
  f32x4 acc0[4];
  const f32x4 vz = {0.f, 0.f, 0.f, 0.f};
#pragma unroll
  for (int i = 0; i < 4; ++i) acc0[i] = vz;
  const int arow = tid >> 2, ak0 = (tid & 3) * 8;
  const int kk = tid >> 3, n0 = (tid & 7) * 8;
  for (int kb = 0; kb < Kp; kb += 32) {
    *(bf16x8*)(sA + arow * 40 + ak0) =
        *(const bf16x8*)(hid + (long)(slot0 + arow) * Ps + kb + ak0);
    int gn0 = bn * 64 + n0;
    float t0[8];
    ld8(B0 + (long)(kb + kk) * 512 + gn0, t0);
#pragma unroll
    for (int j = 0; j < 8; ++j) sB0[(n0 + j) * 40 + kk] = (bf16)t0[j];
    __syncthreads();
    bf16x8 af = *(const bf16x8*)(sA + (wave * 16 + fm) * 40 + quad * 8);
#pragma unroll
    for (int nt = 0; nt < 4; ++nt) {
      bf16x8 bfr = *(const bf16x8*)(sB0 + (nt * 16 + fm) * 40 + quad * 8);
      acc0[nt] = __builtin_amdgcn_mfma_f32_16x16x32_bf16(af, bfr, acc0[nt], 0, 0, 0);
    }
    __syncthreads();
  }
#pragma unroll
  for (int nt = 0; nt < 4; ++nt) {
    int gcol = bn * 64 + nt * 16 + fm;
#pragma unroll
    for (int r = 0; r < 4; ++r) {
      int row = wave * 16 + quad * 4 + r;
      int t = sTok[row];
      float w = sW[row];
      atomicAdd(acc + (long)t * 512 + gcol, acc0[nt][r] * w);
    }
  }
}

// ---------------------------------------------------------------------------
// Fused flash attention (ws bf16 operands).
// ---------------------------------------------------------------------------
__global__ __launch_bounds__(256) void attn_k(const bf16* __restrict__ Q,
                                              const bf16* __restrict__ K,
                                              const bf16* __restrict__ V,
                                              bf16* __restrict__ O) {
  __shared__ __align__(16) bf16 sK[64 * 72];
  __shared__ __align__(16) bf16 sVt[64 * 72];
  __shared__ __align__(16) bf16 sP[4 * 16 * 72];
  const int tid = threadIdx.x, wave = tid >> 6, lane = tid & 63;
  const int fm = lane & 15, quad = lane >> 4;
  const long base = (long)blockIdx.y * Ss * 64;
  const int qrow0 = blockIdx.x * 64 + wave * 16;

  bf16x8 qf[2];
#pragma unroll
  for (int c = 0; c < 2; ++c)
    qf[c] = *(const bf16x8*)(Q + base + (long)(qrow0 + fm) * 64 + c * 32 + quad * 8);

  f32x4 oacc[4];
  const f32x4 vz = {0.f, 0.f, 0.f, 0.f};
#pragma unroll
  for (int i = 0; i < 4; ++i) oacc[i] = vz;
  float m_run[4], l_run[4];
#pragma unroll
  for (int r = 0; r < 4; ++r) { m_run[r] = -1e30f; l_run[r] = 0.f; }

  const int skey = tid >> 2, sd0 = (tid & 3) * 16;
  const int vkey = tid >> 3, vd0 = (tid & 7) * 8;
  bf16* sPw = sP + wave * 16 * 72;

  for (int kt = 0; kt < 16; ++kt) {
    __syncthreads();
    const bf16* Kt = K + base + (long)(kt * 64) * 64;
    *(bf16x8*)(sK + skey * 72 + sd0)     = *(const bf16x8*)(Kt + (long)skey * 64 + sd0);
    *(bf16x8*)(sK + skey * 72 + sd0 + 8) = *(const bf16x8*)(Kt + (long)skey * 64 + sd0 + 8);
    const bf16* Vt = V + base + (long)(kt * 64) * 64;
#pragma unroll
    for (int h = 0; h < 2; ++h) {
      int key = vkey + h * 32;
      bf16x8 vv = *(const bf16x8*)(Vt + (long)key * 64 + vd0);
#pragma unroll
      for (int j = 0; j < 8; ++j) sVt[(vd0 + j) * 72 + key] = vv[j];
    }
    __syncthreads();
    f32x4 sacc[4];
#pragma unroll
    for (int nt = 0; nt < 4; ++nt) sacc[nt] = vz;
#pragma unroll
    for (int c = 0; c < 2; ++c) {
#pragma unroll
      for (int nt = 0; nt < 4; ++nt) {
        bf16x8 kf = *(const bf16x8*)(sK + (nt * 16 + fm) * 72 + c * 32 + quad * 8);
        sacc[nt] = __builtin_amdgcn_mfma_f32_16x16x32_bf16(qf[c], kf, sacc[nt], 0, 0, 0);
      }
    }
#pragma unroll
    for (int nt = 0; nt < 4; ++nt)
#pragma unroll
      for (int r = 0; r < 4; ++r) sacc[nt][r] *= 0.125f;
    float mt[4];
#pragma unroll
    for (int r = 0; r < 4; ++r) {
      float mx = -1e30f;
#pragma unroll
      for (int nt = 0; nt < 4; ++nt) mx = fmaxf(mx, sacc[nt][r]);
      mt[r] = mx;
    }
#pragma unroll
    for (int i = 1; i < 16; i <<= 1) {
#pragma unroll
      for (int r = 0; r < 4; ++r) mt[r] = fmaxf(mt[r], __shfl_xor(mt[r], i, 64));
    }
    float p[4][4], al[4], rs[4];
#pragma unroll
    for (int r = 0; r < 4; ++r) {
      float m_new = fmaxf(m_run[r], mt[r]);
      al[r] = expf(m_run[r] - m_new);
      m_run[r] = m_new;
      float s = 0.f;
#pragma unroll
      for (int nt = 0; nt < 4; ++nt) {
        float e = expf(sacc[nt][r] - m_new);
        p[nt][r] = e; s += e;
      }
      rs[r] = s;
    }
#pragma unroll
    for (int i = 1; i < 16; i <<= 1) {
#pragma unroll
      for (int r = 0; r < 4; ++r) rs[r] += __shfl_xor(rs[r], i, 64);
    }
#pragma unroll
    for (int r = 0; r < 4; ++r) l_run[r] = l_run[r] * al[r] + rs[r];
#pragma unroll
    for (int nt = 0; nt < 4; ++nt)
#pragma unroll
      for (int r = 0; r < 4; ++r) oacc[nt][r] *= al[r];
#pragma unroll
    for (int nt = 0; nt < 4; ++nt)
#pragma unroll
      for (int r = 0; r < 4; ++r)
        sPw[(quad * 4 + r) * 72 + nt * 16 + fm] = (bf16)p[nt][r];
    __syncthreads();
#pragma unroll
    for (int c = 0; c < 2; ++c) {
      bf16x8 pa = *(const bf16x8*)(sPw + fm * 72 + c * 32 + quad * 8);
#pragma unroll
      for (int nt = 0; nt < 4; ++nt) {
        bf16x8 vf = *(const bf16x8*)(sVt + (nt * 16 + fm) * 72 + c * 32 + quad * 8);
        oacc[nt] = __builtin_amdgcn_mfma_f32_16x16x32_bf16(pa, vf, oacc[nt], 0, 0, 0);
      }
    }
  }
#pragma unroll
  for (int nt = 0; nt < 4; ++nt) {
    int col = nt * 16 + fm;
#pragma unroll
    for (int r = 0; r < 4; ++r) {
      int row = qrow0 + quad * 4 + r;
      O[base + (long)row * 64 + col] = (bf16)(oacc[nt][r] / l_run[r]);
    }
  }
}

// ---------------- LayerNorm (D=512) -> bf16 ---------------------------------
template <typename TX, typename TW, int WANT>
__global__ __launch_bounds__(256) void ln_k(const unsigned short* __restrict__ xdet,
                                            const TX* __restrict__ xi,
                                            const TW* __restrict__ w,
                                            const TW* __restrict__ b,
                                            bf16* __restrict__ obf, float eps) {
  if (is_f32(xdet) != WANT) return;
  __shared__ float sm[4];
  long base = (long)blockIdx.x * 512;
  int tid = threadIdx.x;
  float x0 = (float)xi[base + tid], x1 = (float)xi[base + 256 + tid];
  float mean = blocksum(x0 + x1, sm) * (1.f / 512.f);
  float d0 = x0 - mean, d1 = x1 - mean;
  float var = blocksum(d0 * d0 + d1 * d1, sm) * (1.f / 512.f);
  float r = rsqrtf(var + eps);
  obf[base + tid] = (bf16)(d0 * r * (float)w[tid] + (float)b[tid]);
  obf[base + 256 + tid] = (bf16)(d1 * r * (float)w[256 + tid] + (float)b[256 + tid]);
}

// ---------------- RMSNorm (bf16 in, eps 1e-6) -> bf16 -----------------------
__global__ __launch_bounds__(256) void rms_k(const bf16* __restrict__ xi,
                                             bf16* __restrict__ ob) {
  __shared__ float sm[4];
  long base = (long)blockIdx.x * 512;
  int tid = threadIdx.x;
  float x0 = (float)xi[base + tid], x1 = (float)xi[base + 256 + tid];
  float ms = blocksum(x0 * x0 + x1 * x1, sm) * (1.f / 512.f);
  float r = rsqrtf(ms + 1e-6f);
  ob[base + tid] = (bf16)(x0 * r);
  ob[base + 256 + tid] = (bf16)(x1 * r);
}

// ---- q/k l2norm (in place) + v = v*alpha+beta (in place) -------------------
__global__ __launch_bounds__(256) void postproj_k(
    bf16* __restrict__ q, bf16* __restrict__ k, bf16* __restrict__ v,
    const bf16* __restrict__ al, const bf16* __restrict__ be) {
  int wv = threadIdx.x >> 6, lane = threadIdx.x & 63;
  long i = ((long)blockIdx.x * 4 + wv) * 64 + lane;
  float qv = (float)q[i];
  float nq = sqrtf(wavesum(qv * qv));
  q[i] = (bf16)(qv / fmaxf(nq, 1e-12f));
  float kv = (float)k[i];
  float nk = sqrtf(wavesum(kv * kv));
  k[i] = (bf16)(kv / fmaxf(nk, 1e-12f));
  v[i] = (bf16)((float)v[i] * (float)al[i] + (float)be[i]);
}

// ---- o = rms(o)*arms_w*shortcut, in place ----------------------------------
template <typename T, int WANT>
__global__ __launch_bounds__(256) void orms_k(const unsigned short* __restrict__ xdet,
                                              bf16* __restrict__ o,
                                              const T* __restrict__ arms,
                                              const bf16* __restrict__ sc) {
  if (is_f32(xdet) != WANT) return;
  int wv = threadIdx.x >> 6, lane = threadIdx.x & 63;
  long r = (long)blockIdx.x * 4 + wv;
  long i = r * 64 + lane;
  int h = (int)(r >> 11);
  float ov = (float)o[i];
  float ms = wavesum(ov * ov) * (1.f / 64.f);
  float s = rsqrtf(ms + 1e-6f);
  o[i] = (bf16)(ov * s * (float)arms[h * 64 + lane] * (float)sc[i]);
}

// ---------------- router: fp32 LN inside, logits, top-4 ---------------------
template <typename T, int WANT>
__global__ __launch_bounds__(256) void router_k(const unsigned short* __restrict__ xdet,
                                                const float* __restrict__ x2,
                                                const T* __restrict__ lnw,
                                                const T* __restrict__ lnb,
                                                const T* __restrict__ rdw,
                                                const T* __restrict__ ruw,
                                                int* __restrict__ eidx,
                                                float* __restrict__ ew,
                                                int* __restrict__ counts) {
  if (is_f32(xdet) != WANT) return;
  __shared__ float sx[4][512];
  __shared__ float st[4][64];
  __shared__ float sl[4][32];
  int wv = threadIdx.x >> 6, lane = threadIdx.x & 63;
  long t = (long)blockIdx.x * 4 + wv;
  float v[8];
  float s1 = 0.f;
#pragma unroll
  for (int j = 0; j < 8; ++j) { v[j] = x2[t * 512 + lane * 8 + j]; s1 += v[j]; }
  float mean = wavesum(s1) * (1.f / 512.f);
  float s2 = 0.f;
#pragma unroll
  for (int j = 0; j < 8; ++j) { float d = v[j] - mean; s2 += d * d; }
  float rv = rsqrtf(wavesum(s2) * (1.f / 512.f) + 1e-5f);
#pragma unroll
  for (int j = 0; j < 8; ++j)
    sx[wv][lane * 8 + j] = (v[j] - mean) * rv * (float)lnw[lane * 8 + j] + (float)lnb[lane * 8 + j];
  __syncthreads();
  float acc = 0.f;
  for (int d = 0; d < 512; ++d) acc += sx[wv][d] * (float)rdw[d * 64 + lane];
  st[wv][lane] = acc;
  __syncthreads();
  if (lane < 32) {
    float lg = 0.f;
    for (int r = 0; r < 64; ++r) lg += st[wv][r] * (float)ruw[r * 32 + lane];
    sl[wv][lane] = lg;
  }
  __syncthreads();
  if (lane == 0) {
    float vv[32];
#pragma unroll
    for (int e = 0; e < 32; ++e) vv[e] = sl[wv][e];
    int idx[4]; float tv[4];
#pragma unroll
    for (int k = 0; k < 4; ++k) {
      float best = -1e30f; int bi = 0;
      for (int e = 0; e < 32; ++e)
        if (vv[e] > best) { best = vv[e]; bi = e; }
      tv[k] = best; idx[k] = bi; vv[bi] = -1e30f;
    }
    float m = tv[0], s = 0.f, w[4];
#pragma unroll
    for (int k = 0; k < 4; ++k) { w[k] = expf(tv[k] - m); s += w[k]; }
    float inv = 1.f / s;
#pragma unroll
    for (int k = 0; k < 4; ++k) {
      eidx[t * 4 + k] = idx[k];
      ew[t * 4 + k] = w[k] * inv;
      atomicAdd(&counts[idx[k]], 1);
    }
  }
}

// ---------------- binning kernels -------------------------------------------
__global__ void offsets_k(const int* __restrict__ counts, int* __restrict__ segOff,
                          int* __restrict__ tileExp, int* __restrict__ tileStart) {
  if (threadIdx.x != 0) return;
  int off = 0, ti = 0;
  for (int e = 0; e < Ee; ++e) {
    segOff[e] = off;
    int pc = (counts[e] + 63) & ~63;
    for (int i = 0; i < pc / 64; ++i) { tileExp[ti] = e; tileStart[ti] = off + i * 64; ++ti; }
    off += pc;
  }
  for (; ti < 192; ++ti) tileExp[ti] = -1;
}
__global__ void scatter_k(const int* __restrict__ eidx, const float* __restrict__ ew,
                          const int* __restrict__ segOff, int* __restrict__ cursor,
                          int* __restrict__ slotTok, float* __restrict__ slotW) {
  int t = blockIdx.x * 256 + threadIdx.x;
#pragma unroll
  for (int k = 0; k < 4; ++k) {
    int e = eidx[t * 4 + k];
    int pos = atomicAdd(&cursor[e], 1);
    int s = segOff[e] + pos;
    slotTok[s] = t;
    slotW[s] = ew[t * 4 + k];
  }
}
__global__ void pad_k(const int* __restrict__ counts, const int* __restrict__ segOff,
                      int* __restrict__ slotTok, float* __restrict__ slotW) {
  int e = blockIdx.x;
  int c = counts[e], pc = (c + 63) & ~63;
  for (int i = c + threadIdx.x; i < pc; i += 64) {
    int s = segOff[e] + i;
    slotTok[s] = 0;
    slotW[s] = 0.f;
  }
}

// ---------------- misc ----------------
__global__ void zero_k(float* __restrict__ p, long n) {
  long i = (long)blockIdx.x * blockDim.x + threadIdx.x;
  long st = (long)gridDim.x * blockDim.x;
  for (; i < n; i += st) p[i] = 0.f;
}
template <typename TW, typename TO, int WANT>
__global__ __launch_bounds__(256) void final_k(const unsigned short* __restrict__ xdet,
                                               const float* __restrict__ x2,
                                               const TW* __restrict__ lnw,
                                               const TW* __restrict__ lnb,
                                               const float* __restrict__ acc,
                                               TO* __restrict__ out) {
  if (is_f32(xdet) != WANT) return;
  __shared__ float sm[4];
  long base = (long)blockIdx.x * 512;
  int tid = threadIdx.x;
  float x0 = x2[base + tid], x1 = x2[base + 256 + tid];
  float mean = blocksum(x0 + x1, sm) * (1.f / 512.f);
  float d0 = x0 - mean, d1 = x1 - mean;
  float var = blocksum(d0 * d0 + d1 * d1, sm) * (1.f / 512.f);
  float r = rsqrtf(var + 1e-5f);
  float f0 = d0 * r * (float)lnw[tid] + (float)lnb[tid];
  float f1 = d1 * r * (float)lnw[256 + tid] + (float)lnb[256 + tid];
  out[base + tid] = (TO)(x0 + f0 + acc[base + tid]);
  out[base + 256 + tid] = (TO)(x1 + f1 + acc[base + 256 + tid]);
}
template <typename TO, int WANT>
__global__ void loss_k(const unsigned short* __restrict__ xdet,
                       const int* __restrict__ counts, TO* __restrict__ out) {
  if (is_f32(xdet) != WANT) return;
  int lane = threadIdx.x;
  float c = lane < 32 ? (float)counts[lane] : 0.f;
  float mean = wavesum(c) * (1.f / 32.f);
  float d = lane < 32 ? (c - mean) * (c - mean) : 0.f;
  float var = wavesum(d) * (1.f / 31.f);
  if (lane == 0) out[(long)Tt * 512] = (TO)var;
}

// ---------------- host-side dual-dispatch helper for gemm_k -----------------
template <int ACT, int DUAL, int OUTBF, int ACCUM, int RESID, int ASCALE>
static inline void G(dim3 grid, hipStream_t st, const unsigned short* xdet,
                     const bf16* A, long aB, int lda,
                     const void* ascale, long asOff, long asB,
                     const void* B0, long b0Off, const void* B1, long b1Off,
                     long bB, int bK,
                     const void* bias, int biasB,
                     void* C, long cB, int ldc,
                     const void* resid, int resLd,
                     int N, int K, float scale) {
  gemm_k<float, 1, ACT, DUAL, OUTBF, ACCUM, RESID, ASCALE><<<grid, 256, 0, st>>>(
      xdet, A, aB, lda,
      ascale ? (const float*)ascale + asOff : nullptr, asB,
      (const float*)B0 + b0Off, B1 ? (const float*)B1 + b1Off : nullptr, bB, bK,
      bias ? (const float*)bias : nullptr, biasB, C, cB, ldc,
      resid ? (const float*)resid : nullptr, resLd, N, K, scale);
  gemm_k<bf16, 0, ACT, DUAL, OUTBF, ACCUM, RESID, ASCALE><<<grid, 256, 0, st>>>(
      xdet, A, aB, lda,
      ascale ? (const bf16*)ascale + asOff : nullptr, asB,
      (const bf16*)B0 + b0Off, B1 ? (const bf16*)B1 + b1Off : nullptr, bB, bK,
      bias ? (const bf16*)bias : nullptr, biasB, C, cB, ldc,
      resid ? (const bf16*)resid : nullptr, resLd, N, K, scale);
}

// ---------------------------------------------------------------------------
extern "C" void kernel_launch(void* const* d_in, const int* in_sizes, int n_in,
                              void* d_out, int out_size, void* d_ws, size_t ws_size,
                              hipStream_t stream) {
  (void)in_sizes; (void)n_in; (void)out_size;
  const void* x    = d_in[0];
  const void* ln1w = d_in[1];
  const void* ln1b = d_in[2];
  const void* ln2w = d_in[3];
  const void* ln2b = d_in[4];
  const void* q_w  = d_in[5];
  const void* q_b  = d_in[6];
  const void* k_w  = d_in[7];
  const void* k_b  = d_in[8];
  const void* v_w  = d_in[9];
  const void* v_b  = d_in[10];
  const void* aw1  = d_in[11];
  const void* ab1  = d_in[12];
  const void* aw2  = d_in[13];
  const void* ab2  = d_in[14];
  const void* bw   = d_in[15];
  const void* bbv  = d_in[16];
  const void* scw1 = d_in[17];
  const void* scb1 = d_in[18];
  const void* scw2 = d_in[19];
  const void* scb2 = d_in[20];
  const void* arms = d_in[21];
  const void* l1w  = d_in[22];
  const void* l1b  = d_in[23];
  const void* outw = d_in[24];
  const void* outb = d_in[25];
  const void* shrms= d_in[26];
  const void* shw1 = d_in[27];
  const void* shw2 = d_in[28];
  const void* shw3 = d_in[29];
  const void* rw1  = d_in[30];
  const void* rw2  = d_in[31];
  const void* rw3  = d_in[32];
  const void* rdw  = d_in[33];
  const void* ruw  = d_in[34];
  const unsigned short* xdet = (const unsigned short*)x;

  // ---- workspace map. Base 16 MiB (proven safe); hid grows with ws_size.
  // Attention: xn[0,2) qh[2,4) kh[4,6) vh[6,8) beta[8,10) ah[10,11)
  //            alpha[12,14) sch[8,9) shct[14,16) oatt[8,10) conc[2,4)
  //            x2[4,8)fp32
  // MoE:       xfb[0,2) rbb[2,4) x2[4,8) hdr[8MB,8MB+256KB) acc[12,16)fp32
  //            hid = [8MB+256KB,12MB) or [16MB, ws_size)
  constexpr size_t MB = 1u << 20;
  char* base = (char*)d_ws;
  bf16* xn    = (bf16*)(base + 0 * MB);
  bf16* qh    = (bf16*)(base + 2 * MB);
  bf16* kh    = (bf16*)(base + 4 * MB);
  bf16* vh    = (bf16*)(base + 6 * MB);
  bf16* beta  = (bf16*)(base + 8 * MB);
  bf16* ah    = (bf16*)(base + 10 * MB);
  bf16* alpha = (bf16*)(base + 12 * MB);
  bf16* sch   = (bf16*)(base + 8 * MB);
  bf16* shct  = (bf16*)(base + 14 * MB);
  bf16* oatt  = (bf16*)(base + 8 * MB);
  bf16* conc  = (bf16*)(base + 2 * MB);
  float* x2   = (float*)(base + 4 * MB);
  bf16* xfb   = (bf16*)(base + 0 * MB);
  bf16* rbb   = (bf16*)(base + 2 * MB);
  float* acc  = (float*)(base + 12 * MB);
  // header
  int*   hcnt = (int*)(base + 8 * MB);        // counts[32]
  int*   hcur = hcnt + 32;                    // cursor[32]
  int*   hseg = hcnt + 64;                    // segOff[32]
  int*   hte  = hcnt + 96;                    // tileExp[192]
  int*   hts  = hcnt + 288;                   // tileStart[192]
  int*   heidx= hcnt + 512;                   // eidx[8192]
  float* hew  = (float*)(hcnt + 512 + 8192);  // ew[8192]
  int*   hstok= hcnt + 512 + 16384;           // slotTok[10240]
  float* hsw  = (float*)(hcnt + 512 + 16384 + 10240);  // slotW[10240]
  // hidden buffer
  bf16* hid; long hidElems;
  if (ws_size >= 20 * MB) {
    hid = (bf16*)(base + 16 * MB);
    hidElems = (long)(ws_size - 16 * MB) / 2;
  } else {
    hid = (bf16*)(base + 8 * MB + 256 * 1024);
    hidElems = (long)(4 * MB - 256 * 1024) / 2;
  }
  int PsR = (int)((hidElems / SLOTCAP / 32) * 32);
  if (PsR > F2f) PsR = F2f;
  if (PsR < 32) PsR = 32;                      // defensive (never hit at >=16MiB)
  int PsS, zBsh;
  if (hidElems >= (long)Tt * F3f) {
    PsS = F3f;
    zBsh = (int)(hidElems / ((long)Tt * F3f)); if (zBsh > NSs) zBsh = NSs;
  } else {
    PsS = (int)((hidElems / Tt / 32) * 32); if (PsS > F3f) PsS = F3f;
    zBsh = 1;
  }

  // ---- attention sublayer ----
  ln_k<float, float, 1><<<Tt, 256, 0, stream>>>(xdet, (const float*)x, (const float*)ln1w, (const float*)ln1b, xn, 1e-5f);
  ln_k<bf16, bf16, 0><<<Tt, 256, 0, stream>>>(xdet, (const bf16*)x, (const bf16*)ln1w, (const bf16*)ln1b, xn, 1e-5f);

  G<1,0,1,0,0,0>(dim3(32,1,8), stream, xdet, xn,0,512, nullptr,0,0, q_w,0,nullptr,0,(long)512*64,64, q_b,64, qh,(long)Tt*64,64, nullptr,0, 64,512,1.f);
  G<1,0,1,0,0,0>(dim3(32,1,8), stream, xdet, xn,0,512, nullptr,0,0, k_w,0,nullptr,0,(long)512*64,64, k_b,64, kh,(long)Tt*64,64, nullptr,0, 64,512,1.f);
  G<1,0,1,0,0,0>(dim3(32,1,8), stream, xdet, xn,0,512, nullptr,0,0, v_w,0,nullptr,0,(long)512*64,64, v_b,64, vh,(long)Tt*64,64, nullptr,0, 64,512,1.f);
  G<2,0,1,0,0,0>(dim3(32,1,8), stream, xdet, xn,0,512, nullptr,0,0, bw,0,nullptr,0,(long)512*64,64, bbv,64, beta,(long)Tt*64,64, nullptr,0, 64,512,1.f);
  G<0,0,1,0,0,0>(dim3(32,1,8), stream, xdet, xn,0,512, nullptr,0,0, aw1,0,nullptr,0,(long)512*32,32, ab1,32, ah,(long)Tt*32,32, nullptr,0, 32,512,1.f);
  G<2,0,1,0,0,0>(dim3(32,1,8), stream, xdet, ah,(long)Tt*32,32, nullptr,0,0, aw2,0,nullptr,0,(long)32*64,64, ab2,64, alpha,(long)Tt*64,64, nullptr,0, 64,32,1.f);

  postproj_k<<<NHh * Tt / 4, 256, 0, stream>>>(qh, kh, vh, alpha, beta);

  G<0,0,1,0,0,0>(dim3(32,1,8), stream, xdet, xn,0,512, nullptr,0,0, scw1,0,nullptr,0,(long)512*32,32, scb1,32, sch,(long)Tt*32,32, nullptr,0, 32,512,1.f);
  G<2,0,1,0,0,0>(dim3(32,1,8), stream, xdet, sch,(long)Tt*32,32, nullptr,0,0, scw2,0,nullptr,0,(long)32*64,64, scb2,64, shct,(long)Tt*64,64, nullptr,0, 64,32,1.f);

  attn_k<<<dim3(16, 16), 256, 0, stream>>>(qh, kh, vh, oatt);

  orms_k<float, 1><<<NHh * Tt / 4, 256, 0, stream>>>(xdet, oatt, (const float*)arms, shct);
  orms_k<bf16, 0><<<NHh * Tt / 4, 256, 0, stream>>>(xdet, oatt, (const bf16*)arms, shct);

  G<0,0,1,0,0,0>(dim3(32,1,8), stream, xdet, oatt,(long)Tt*64,64, nullptr,0,0, l1w,0,nullptr,0,(long)64*64,64, l1b,64, conc,64,512, nullptr,0, 64,64,1.f);
  G<0,0,0,0,1,0>(dim3(32,8,1), stream, xdet, conc,0,512, nullptr,0,0, outw,0,nullptr,0,0,512, outb,0, x2,0,512, x,512, 512,512,1.f);

  // ---- MoE sublayer ----
  ln_k<float, float, 1><<<Tt, 256, 0, stream>>>(xdet, x2, (const float*)ln2w, (const float*)ln2b, xfb, 1e-5f);
  ln_k<float, bf16, 0><<<Tt, 256, 0, stream>>>(xdet, x2, (const bf16*)ln2w, (const bf16*)ln2b, xfb, 1e-5f);
  rms_k<<<Tt, 256, 0, stream>>>(xfb, rbb);
  zero_k<<<256, 256, 0, stream>>>(acc, (long)Tt * 512);
  zero_k<<<1, 64, 0, stream>>>((float*)hcnt, 64);   // counts + cursor
  router_k<float, 1><<<Tt / 4, 256, 0, stream>>>(xdet, x2, (const float*)ln2w, (const float*)ln2b, (const float*)rdw, (const float*)ruw, heidx, hew, hcnt);
  router_k<bf16, 0><<<Tt / 4, 256, 0, stream>>>(xdet, x2, (const bf16*)ln2w, (const bf16*)ln2b, (const bf16*)rdw, (const bf16*)ruw, heidx, hew, hcnt);
  offsets_k<<<1, 64, 0, stream>>>(hcnt, hseg, hte, hts);
  scatter_k<<<Tt / 256, 256, 0, stream>>>(heidx, hew, hseg, hcur, hstok, hsw);
  pad_k<<<Ee, 64, 0, stream>>>(hcnt, hseg, hstok, hsw);

  // shared experts: SwiGLU (ascale = rmsnorm weight fold) then w2 @ 1/8
  for (int n0e = 0; n0e < NSs; n0e += zBsh) {
    int zc = NSs - n0e < zBsh ? NSs - n0e : zBsh;
    for (int off = 0; off < F3f; off += PsS) {
      int Np = F3f - off < PsS ? F3f - off : PsS;
      G<0,1,1,0,0,1>(dim3(32,(Np+63)/64,zc), stream, xdet, rbb,0,512,
                     shrms,(long)n0e*512,512,
                     shw1,(long)n0e*512*F3f + off, shw3,(long)n0e*512*F3f + off,
                     (long)512*F3f, F3f,
                     nullptr,0, hid,(long)Tt*PsS,PsS, nullptr,0, Np,512,1.f);
      G<0,0,0,1,0,0>(dim3(32,8,zc), stream, xdet, hid,(long)Tt*PsS,PsS, nullptr,0,0,
                     shw2,(long)n0e*F3f*512 + (long)off*512, nullptr,0,
                     (long)F3f*512, 512,
                     nullptr,0, acc,0,512, nullptr,0, 512,Np,0.125f);
    }
  }

  // routed experts: sparse token-gathered, scatter-add with routing weight
  for (int off = 0; off < F2f; off += PsR) {
    int Np = F2f - off < PsR ? F2f - off : PsR;
    dim3 g1(MAXTILE, (Np + 63) / 64);
    moe1_k<float, 1><<<g1, 256, 0, stream>>>(xdet, hte, hts, hstok, xfb, (const float*)rw1, (const float*)rw3, hid, PsR, off, Np);
    moe1_k<bf16, 0><<<g1, 256, 0, stream>>>(xdet, hte, hts, hstok, xfb, (const bf16*)rw1, (const bf16*)rw3, hid, PsR, off, Np);
    dim3 g2(MAXTILE, 8);
    moe2_k<float, 1><<<g2, 256, 0, stream>>>(xdet, hte, hts, hstok, hsw, hid, PsR, off, Np, (const float*)rw2, acc);
    moe2_k<bf16, 0><<<g2, 256, 0, stream>>>(xdet, hte, hts, hstok, hsw, hid, PsR, off, Np, (const bf16*)rw2, acc);
  }

  final_k<float, float, 1><<<Tt, 256, 0, stream>>>(xdet, x2, (const float*)ln2w, (const float*)ln2b, acc, (float*)d_out);
  final_k<bf16, bf16, 0><<<Tt, 256, 0, stream>>>(xdet, x2, (const bf16*)ln2w, (const bf16*)ln2b, acc, (bf16*)d_out);
  loss_k<float, 1><<<1, 64, 0, stream>>>(xdet, hcnt, (float*)d_out);
  loss_k<bf16, 0><<<1, 64, 0, stream>>>(xdet, hcnt, (bf16*)d_out);
}

// Round 8
// 1196.989 us; speedup vs baseline: 4.2194x; 1.1196x over previous
//
#include <hip/hip_runtime.h>
#include <cmath>
#include <cstdint>

// ---------------------------------------------------------------------------
// TransformerEncoderLayer (attention + MoE) on MI355X, fp32 acc.
// Round 8: kill LDS bank conflicts (r7 profile: SQ_LDS_BANK_CONFLICT=1.05e8 on
// the shared-expert SwiGLU dispatch = ~66% of its 260us). B-tile staging is now
// k-major: per-k-row coalesced global loads -> each lane holds 8 k-consecutive
// values -> single ds_write_b128; starts (20n+4w)%32 tile all 32 banks
// (capacity-optimal, zero excess conflicts). Same fix in attn_k's V staging
// (stride-72 scalar transpose had the identical 8m*36%32==0 collision).
// Pipeline/memory map identical to r7.
// ---------------------------------------------------------------------------

typedef __bf16 bf16;
typedef __bf16 bf16x8 __attribute__((ext_vector_type(8)));
typedef float  f32x4  __attribute__((ext_vector_type(4)));

static constexpr int Bb = 2, Ss = 1024, Dd = 512, NHh = 8, HDd = 64;
static constexpr int Tt = Bb * Ss;           // 2048 tokens
static constexpr int NSs = 8, F3f = 1536;
static constexpr int Ee = 32, F2f = 1024;
static constexpr int SLOTCAP = 10240;        // 8192 + worst-case pad (10208)
static constexpr int MAXTILE = 160;

// ---------------- helpers ----------------
__device__ inline float wavesum(float v) {
#pragma unroll
  for (int i = 1; i < 64; i <<= 1) v += __shfl_xor(v, i, 64);
  return v;
}
__device__ inline float blocksum(float v, float* sm) {
  v = wavesum(v);
  int wv = threadIdx.x >> 6;
  __syncthreads();
  if ((threadIdx.x & 63) == 0) sm[wv] = v;
  __syncthreads();
  return (sm[0] + sm[1]) + (sm[2] + sm[3]);
}
__device__ inline float silu_f(float x) { return x / (1.f + expf(-x)); }
__device__ inline float sigm_f(float x) { return 1.f / (1.f + expf(-x)); }

// Inline dtype classifier on d_in[0] (x ~ N(0,1)); 1 = fp32 buffer.
__device__ inline int is_f32(const unsigned short* __restrict__ xr) {
  int good = 0;
#pragma unroll
  for (int i = 0; i < 32; ++i) {
    unsigned e = (xr[2 * i] >> 7) & 0xFF;
    good += (e >= 110 && e <= 140);
  }
  return good < 16;
}

// ---------------------------------------------------------------------------
// Flexible MFMA GEMM. B staged k-major (conflict-free b128 LDS writes).
// Fragment layouts (learn_hip m89/m91): A[m=lane&15][k=quad*8+j],
// B[k=quad*8+j][n=lane&15] from B^T tile, C row=quad*4+reg col=lane&15.
// ---------------------------------------------------------------------------
template <typename TB, int WANT, int ACT, int DUAL, int OUTBF, int ACCUM,
          int RESID, int ASCALE>
__global__ __launch_bounds__(256) void gemm_k(
    const unsigned short* __restrict__ xdet,
    const bf16* __restrict__ A, long aBatch, int lda,
    const TB* __restrict__ ascale, long asBatch,
    const TB* __restrict__ B0, const TB* __restrict__ B1, long bBatch, int bK,
    const TB* __restrict__ bias, int biasBatch,
    void* __restrict__ Cv, long cBatch, int ldc,
    const TB* __restrict__ resid, int resLd,
    int N, int K, float scale) {
  if (is_f32(xdet) != WANT) return;
  __shared__ __align__(16) bf16 sA[64 * 40];
  __shared__ __align__(16) bf16 sB0[64 * 40];
  __shared__ __align__(16) bf16 sB1[64 * 40];

  const int tid = threadIdx.x;
  const int wave = tid >> 6, lane = tid & 63;
  const int fm = lane & 15, quad = lane >> 4;
  const int bm = blockIdx.x, bn = blockIdx.y, z = blockIdx.z;

  const bf16* Az = A + (long)z * aBatch;
  const TB* B0z = B0 + (long)z * bBatch;
  const TB* B1z = DUAL ? (B1 + (long)z * bBatch) : nullptr;
  const TB* asz = ASCALE ? (ascale + (long)z * asBatch) : nullptr;

  f32x4 acc0[4], acc1[4];
  const f32x4 vzero = {0.f, 0.f, 0.f, 0.f};
#pragma unroll
  for (int i = 0; i < 4; ++i) { acc0[i] = vzero; acc1[i] = vzero; }

  const int arow = tid >> 2, ak0 = (tid & 3) * 8;   // A staging (row-major)
  const int gn = bn * 64 + lane;                    // B staging (k-major)
  const int wch = wave * 8;                         // this wave's k-chunk

  for (int kb = 0; kb < K; kb += 32) {
    // ---- A tile (vector row copy; bank-capacity-optimal) ----
    bf16x8 av = *(const bf16x8*)(Az + (long)(bm * 64 + arow) * lda + kb + ak0);
    if (ASCALE) {
#pragma unroll
      for (int j = 0; j < 8; ++j)
        av[j] = (bf16)((float)av[j] * (float)asz[kb + ak0 + j]);
    }
    *(bf16x8*)(sA + arow * 40 + ak0) = av;
    // ---- B tile: k-major loads, b128 writes to [n][k] (conflict-free) ----
    bf16x8 bv, cv;
    if (gn < N) {
      const TB* bp = B0z + (long)(kb + wch) * bK + gn;
#pragma unroll
      for (int j = 0; j < 8; ++j) bv[j] = (bf16)(float)bp[(long)j * bK];
      if (DUAL) {
        const TB* cp = B1z + (long)(kb + wch) * bK + gn;
#pragma unroll
        for (int j = 0; j < 8; ++j) cv[j] = (bf16)(float)cp[(long)j * bK];
      }
    } else {
#pragma unroll
      for (int j = 0; j < 8; ++j) { bv[j] = (bf16)0.f; if (DUAL) cv[j] = (bf16)0.f; }
    }
    *(bf16x8*)(sB0 + lane * 40 + wch) = bv;
    if (DUAL) *(bf16x8*)(sB1 + lane * 40 + wch) = cv;
    __syncthreads();
    bf16x8 af = *(const bf16x8*)(sA + (wave * 16 + fm) * 40 + quad * 8);
#pragma unroll
    for (int nt = 0; nt < 4; ++nt) {
      bf16x8 bfr = *(const bf16x8*)(sB0 + (nt * 16 + fm) * 40 + quad * 8);
      acc0[nt] = __builtin_amdgcn_mfma_f32_16x16x32_bf16(af, bfr, acc0[nt], 0, 0, 0);
      if (DUAL) {
        bf16x8 bg = *(const bf16x8*)(sB1 + (nt * 16 + fm) * 40 + quad * 8);
        acc1[nt] = __builtin_amdgcn_mfma_f32_16x16x32_bf16(af, bg, acc1[nt], 0, 0, 0);
      }
    }
    __syncthreads();
  }

#pragma unroll
  for (int nt = 0; nt < 4; ++nt) {
    int gcol = bn * 64 + nt * 16 + fm;
    if (gcol >= N) continue;
#pragma unroll
    for (int r = 0; r < 4; ++r) {
      int grow = bm * 64 + wave * 16 + quad * 4 + r;
      float v;
      if (DUAL) {
        v = silu_f(acc0[nt][r]) * acc1[nt][r];
      } else {
        v = acc0[nt][r] * scale;
        if (bias) v += (float)bias[z * biasBatch + gcol];
        if (ACT == 1) v = silu_f(v);
        else if (ACT == 2) v = sigm_f(v);
      }
      if (RESID) v += (float)resid[(long)grow * resLd + gcol];
      long ci = (long)z * cBatch + (long)grow * ldc + gcol;
      if (ACCUM) atomicAdd((float*)Cv + ci, v);
      else if (OUTBF) ((bf16*)Cv)[ci] = (bf16)v;
      else ((float*)Cv)[ci] = v;
    }
  }
}

// ---------------------------------------------------------------------------
// Sparse routed expert stage 1: gathered dual-SwiGLU GEMM into hidden buffer.
// ---------------------------------------------------------------------------
template <typename TB, int WANT>
__global__ __launch_bounds__(256) void moe1_k(
    const unsigned short* __restrict__ xdet,
    const int* __restrict__ tileExp, const int* __restrict__ tileStart,
    const int* __restrict__ slotTok,
    const bf16* __restrict__ xfb,
    const TB* __restrict__ W1, const TB* __restrict__ W3,
    bf16* __restrict__ hid, int Ps, int colOff, int Np) {
  if (is_f32(xdet) != WANT) return;
  int e = tileExp[blockIdx.x];
  if (e < 0) return;
  int slot0 = tileStart[blockIdx.x];
  __shared__ int sTok[64];
  __shared__ __align__(16) bf16 sA[64 * 40];
  __shared__ __align__(16) bf16 sB0[64 * 40];
  __shared__ __align__(16) bf16 sB1[64 * 40];
  const int tid = threadIdx.x;
  const int wave = tid >> 6, lane = tid & 63;
  const int fm = lane & 15, quad = lane >> 4;
  if (tid < 64) sTok[tid] = slotTok[slot0 + tid];
  __syncthreads();
  const TB* B0 = W1 + (long)e * 512 * F2f + colOff;
  const TB* B1 = W3 + (long)e * 512 * F2f + colOff;
  const int bn = blockIdx.y;
  f32x4 acc0[4], acc1[4];
  const f32x4 vz = {0.f, 0.f, 0.f, 0.f};
#pragma unroll
  for (int i = 0; i < 4; ++i) { acc0[i] = vz; acc1[i] = vz; }
  const int arow = tid >> 2, ak0 = (tid & 3) * 8;
  const int gn = bn * 64 + lane;
  const int wch = wave * 8;
  for (int kb = 0; kb < 512; kb += 32) {
    int tok = sTok[arow];
    *(bf16x8*)(sA + arow * 40 + ak0) =
        *(const bf16x8*)(xfb + (long)tok * 512 + kb + ak0);
    bf16x8 bv, cv;
    if (gn < Np) {
      const TB* bp = B0 + (long)(kb + wch) * F2f + gn;
      const TB* cp = B1 + (long)(kb + wch) * F2f + gn;
#pragma unroll
      for (int j = 0; j < 8; ++j) {
        bv[j] = (bf16)(float)bp[(long)j * F2f];
        cv[j] = (bf16)(float)cp[(long)j * F2f];
      }
    } else {
#pragma unroll
      for (int j = 0; j < 8; ++j) { bv[j] = (bf16)0.f; cv[j] = (bf16)0.f; }
    }
    *(bf16x8*)(sB0 + lane * 40 + wch) = bv;
    *(bf16x8*)(sB1 + lane * 40 + wch) = cv;
    __syncthreads();
    bf16x8 af = *(const bf16x8*)(sA + (wave * 16 + fm) * 40 + quad * 8);
#pragma unroll
    for (int nt = 0; nt < 4; ++nt) {
      bf16x8 bfr = *(const bf16x8*)(sB0 + (nt * 16 + fm) * 40 + quad * 8);
      acc0[nt] = __builtin_amdgcn_mfma_f32_16x16x32_bf16(af, bfr, acc0[nt], 0, 0, 0);
      bf16x8 bg = *(const bf16x8*)(sB1 + (nt * 16 + fm) * 40 + quad * 8);
      acc1[nt] = __builtin_amdgcn_mfma_f32_16x16x32_bf16(af, bg, acc1[nt], 0, 0, 0);
    }
    __syncthreads();
  }
#pragma unroll
  for (int nt = 0; nt < 4; ++nt) {
    int gcol = bn * 64 + nt * 16 + fm;
    if (gcol >= Np) continue;
#pragma unroll
    for (int r = 0; r < 4; ++r) {
      int row = wave * 16 + quad * 4 + r;
      hid[(long)(slot0 + row) * Ps + gcol] =
          (bf16)(silu_f(acc0[nt][r]) * acc1[nt][r]);
    }
  }
}

// ---------------------------------------------------------------------------
// Sparse routed expert stage 2: hidden @ W2, scatter-add w*out into acc.
// ---------------------------------------------------------------------------
template <typename TB, int WANT>
__global__ __launch_bounds__(256) void moe2_k(
    const unsigned short* __restrict__ xdet,
    const int* __restrict__ tileExp, const int* __restrict__ tileStart,
    const int* __restrict__ slotTok, const float* __restrict__ slotW,
    const bf16* __restrict__ hid, int Ps, int colOff, int Kp,
    const TB* __restrict__ W2, float* __restrict__ acc) {
  if (is_f32(xdet) != WANT) return;
  int e = tileExp[blockIdx.x];
  if (e < 0) return;
  int slot0 = tileStart[blockIdx.x];
  __shared__ int sTok[64];
  __shared__ float sW[64];
  __shared__ __align__(16) bf16 sA[64 * 40];
  __shared__ __align__(16) bf16 sB0[64 * 40];
  const int tid = threadIdx.x;
  const int wave = tid >> 6, lane = tid & 63;
  const int fm = lane & 15, quad = lane >> 4;
  if (tid < 64) { sTok[tid] = slotTok[slot0 + tid]; sW[tid] = slotW[slot0 + tid]; }
  __syncthreads();
  const TB* B0 = W2 + (long)e * F2f * 512 + (long)colOff * 512;
  const int bn = blockIdx.y;
  f32x4 acc0[4];
  const f32x4 vz = {0.f, 0.f, 0.f, 0.f};
#pragma unroll
  for (int i = 0; i < 4; ++i) acc0[i] = vz;
  const int arow = tid >> 2, ak0 = (tid & 3) * 8;
  const int gn = bn * 64 + lane;
  const int wch = wave * 8;
  for (int kb = 0; kb < Kp; kb += 32) {
    *(bf16x8*)(sA + arow * 40 + ak0) =
        *(const bf16x8*)(hid + (long)(slot0 + arow) * Ps + kb + ak0);
    const TB* bp = B0 + (long)(kb + wch) * 512 + gn;
    bf16x8 bv;
#pragma unroll
    for (int j = 0; j < 8; ++j) bv[j] = (bf16)(float)bp[(long)j * 512];
    *(bf16x8*)(sB0 + lane * 40 + wch) = bv;
    __syncthreads();
    bf16x8 af = *(const bf16x8*)(sA + (wave * 16 + fm) * 40 + quad * 8);
#pragma unroll
    for (int nt = 0; nt < 4; ++nt) {
      bf16x8 bfr = *(const bf16x8*)(sB0 + (nt * 16 + fm) * 40 + quad * 8);
      acc0[nt] = __builtin_amdgcn_mfma_f32_16x16x32_bf16(af, bfr, acc0[nt], 0, 0, 0);
    }
    __syncthreads();
  }
#pragma unroll
  for (int nt = 0; nt < 4; ++nt) {
    int gcol = bn * 64 + nt * 16 + fm;
#pragma unroll
    for (int r = 0; r < 4; ++r) {
      int row = wave * 16 + quad * 4 + r;
      int t = sTok[row];
      float w = sW[row];
      atomicAdd(acc + (long)t * 512 + gcol, acc0[nt][r] * w);
    }
  }
}

// ---------------------------------------------------------------------------
// Fused flash attention. V staged k-major (conflict-free b128 writes).
// ---------------------------------------------------------------------------
__global__ __launch_bounds__(256) void attn_k(const bf16* __restrict__ Q,
                                              const bf16* __restrict__ K,
                                              const bf16* __restrict__ V,
                                              bf16* __restrict__ O) {
  __shared__ __align__(16) bf16 sK[64 * 72];
  __shared__ __align__(16) bf16 sVt[64 * 72];
  __shared__ __align__(16) bf16 sP[4 * 16 * 72];
  const int tid = threadIdx.x, wave = tid >> 6, lane = tid & 63;
  const int fm = lane & 15, quad = lane >> 4;
  const long base = (long)blockIdx.y * Ss * 64;
  const int qrow0 = blockIdx.x * 64 + wave * 16;

  bf16x8 qf[2];
#pragma unroll
  for (int c = 0; c < 2; ++c)
    qf[c] = *(const bf16x8*)(Q + base + (long)(qrow0 + fm) * 64 + c * 32 + quad * 8);

  f32x4 oacc[4];
  const f32x4 vz = {0.f, 0.f, 0.f, 0.f};
#pragma unroll
  for (int i = 0; i < 4; ++i) oacc[i] = vz;
  float m_run[4], l_run[4];
#pragma unroll
  for (int r = 0; r < 4; ++r) { m_run[r] = -1e30f; l_run[r] = 0.f; }

  const int skey = tid >> 2, sd0 = (tid & 3) * 16;
  bf16* sPw = sP + wave * 16 * 72;

  for (int kt = 0; kt < 16; ++kt) {
    __syncthreads();
    const bf16* Kt = K + base + (long)(kt * 64) * 64;
    *(bf16x8*)(sK + skey * 72 + sd0)     = *(const bf16x8*)(Kt + (long)skey * 64 + sd0);
    *(bf16x8*)(sK + skey * 72 + sd0 + 8) = *(const bf16x8*)(Kt + (long)skey * 64 + sd0 + 8);
    // V staged k-major: lane holds keys wave*16..+15 for its d column.
    const bf16* Vt = V + base + (long)(kt * 64) * 64;
    {
      bf16x8 v0, v1;
#pragma unroll
      for (int j = 0; j < 8; ++j) v0[j] = Vt[(long)(wave * 16 + j) * 64 + lane];
#pragma unroll
      for (int j = 0; j < 8; ++j) v1[j] = Vt[(long)(wave * 16 + 8 + j) * 64 + lane];
      *(bf16x8*)(sVt + lane * 72 + wave * 16) = v0;
      *(bf16x8*)(sVt + lane * 72 + wave * 16 + 8) = v1;
    }
    __syncthreads();
    f32x4 sacc[4];
#pragma unroll
    for (int nt = 0; nt < 4; ++nt) sacc[nt] = vz;
#pragma unroll
    for (int c = 0; c < 2; ++c) {
#pragma unroll
      for (int nt = 0; nt < 4; ++nt) {
        bf16x8 kf = *(const bf16x8*)(sK + (nt * 16 + fm) * 72 + c * 32 + quad * 8);
        sacc[nt] = __builtin_amdgcn_mfma_f32_16x16x32_bf16(qf[c], kf, sacc[nt], 0, 0, 0);
      }
    }
#pragma unroll
    for (int nt = 0; nt < 4; ++nt)
#pragma unroll
      for (int r = 0; r < 4; ++r) sacc[nt][r] *= 0.125f;
    float mt[4];
#pragma unroll
    for (int r = 0; r < 4; ++r) {
      float mx = -1e30f;
#pragma unroll
      for (int nt = 0; nt < 4; ++nt) mx = fmaxf(mx, sacc[nt][r]);
      mt[r] = mx;
    }
#pragma unroll
    for (int i = 1; i < 16; i <<= 1) {
#pragma unroll
      for (int r = 0; r < 4; ++r) mt[r] = fmaxf(mt[r], __shfl_xor(mt[r], i, 64));
    }
    float p[4][4], al[4], rs[4];
#pragma unroll
    for (int r = 0; r < 4; ++r) {
      float m_new = fmaxf(m_run[r], mt[r]);
      al[r] = expf(m_run[r] - m_new);
      m_run[r] = m_new;
      float s = 0.f;
#pragma unroll
      for (int nt = 0; nt < 4; ++nt) {
        float e = expf(sacc[nt][r] - m_new);
        p[nt][r] = e; s += e;
      }
      rs[r] = s;
    }
#pragma unroll
    for (int i = 1; i < 16; i <<= 1) {
#pragma unroll
      for (int r = 0; r < 4; ++r) rs[r] += __shfl_xor(rs[r], i, 64);
    }
#pragma unroll
    for (int r = 0; r < 4; ++r) l_run[r] = l_run[r] * al[r] + rs[r];
#pragma unroll
    for (int nt = 0; nt < 4; ++nt)
#pragma unroll
      for (int r = 0; r < 4; ++r) oacc[nt][r] *= al[r];
#pragma unroll
    for (int nt = 0; nt < 4; ++nt)
#pragma unroll
      for (int r = 0; r < 4; ++r)
        sPw[(quad * 4 + r) * 72 + nt * 16 + fm] = (bf16)p[nt][r];
    __syncthreads();
#pragma unroll
    for (int c = 0; c < 2; ++c) {
      bf16x8 pa = *(const bf16x8*)(sPw + fm * 72 + c * 32 + quad * 8);
#pragma unroll
      for (int nt = 0; nt < 4; ++nt) {
        bf16x8 vf = *(const bf16x8*)(sVt + (nt * 16 + fm) * 72 + c * 32 + quad * 8);
        oacc[nt] = __builtin_amdgcn_mfma_f32_16x16x32_bf16(pa, vf, oacc[nt], 0, 0, 0);
      }
    }
  }
#pragma unroll
  for (int nt = 0; nt < 4; ++nt) {
    int col = nt * 16 + fm;
#pragma unroll
    for (int r = 0; r < 4; ++r) {
      int row = qrow0 + quad * 4 + r;
      O[base + (long)row * 64 + col] = (bf16)(oacc[nt][r] / l_run[r]);
    }
  }
}

// ---------------- LayerNorm (D=512) -> bf16 ---------------------------------
template <typename TX, typename TW, int WANT>
__global__ __launch_bounds__(256) void ln_k(const unsigned short* __restrict__ xdet,
                                            const TX* __restrict__ xi,
                                            const TW* __restrict__ w,
                                            const TW* __restrict__ b,
                                            bf16* __restrict__ obf, float eps) {
  if (is_f32(xdet) != WANT) return;
  __shared__ float sm[4];
  long base = (long)blockIdx.x * 512;
  int tid = threadIdx.x;
  float x0 = (float)xi[base + tid], x1 = (float)xi[base + 256 + tid];
  float mean = blocksum(x0 + x1, sm) * (1.f / 512.f);
  float d0 = x0 - mean, d1 = x1 - mean;
  float var = blocksum(d0 * d0 + d1 * d1, sm) * (1.f / 512.f);
  float r = rsqrtf(var + eps);
  obf[base + tid] = (bf16)(d0 * r * (float)w[tid] + (float)b[tid]);
  obf[base + 256 + tid] = (bf16)(d1 * r * (float)w[256 + tid] + (float)b[256 + tid]);
}

// ---------------- RMSNorm (bf16 in, eps 1e-6) -> bf16 -----------------------
__global__ __launch_bounds__(256) void rms_k(const bf16* __restrict__ xi,
                                             bf16* __restrict__ ob) {
  __shared__ float sm[4];
  long base = (long)blockIdx.x * 512;
  int tid = threadIdx.x;
  float x0 = (float)xi[base + tid], x1 = (float)xi[base + 256 + tid];
  float ms = blocksum(x0 * x0 + x1 * x1, sm) * (1.f / 512.f);
  float r = rsqrtf(ms + 1e-6f);
  ob[base + tid] = (bf16)(x0 * r);
  ob[base + 256 + tid] = (bf16)(x1 * r);
}

// ---- q/k l2norm (in place) + v = v*alpha+beta (in place) -------------------
__global__ __launch_bounds__(256) void postproj_k(
    bf16* __restrict__ q, bf16* __restrict__ k, bf16* __restrict__ v,
    const bf16* __restrict__ al, const bf16* __restrict__ be) {
  int wv = threadIdx.x >> 6, lane = threadIdx.x & 63;
  long i = ((long)blockIdx.x * 4 + wv) * 64 + lane;
  float qv = (float)q[i];
  float nq = sqrtf(wavesum(qv * qv));
  q[i] = (bf16)(qv / fmaxf(nq, 1e-12f));
  float kv = (float)k[i];
  float nk = sqrtf(wavesum(kv * kv));
  k[i] = (bf16)(kv / fmaxf(nk, 1e-12f));
  v[i] = (bf16)((float)v[i] * (float)al[i] + (float)be[i]);
}

// ---- o = rms(o)*arms_w*shortcut, in place ----------------------------------
template <typename T, int WANT>
__global__ __launch_bounds__(256) void orms_k(const unsigned short* __restrict__ xdet,
                                              bf16* __restrict__ o,
                                              const T* __restrict__ arms,
                                              const bf16* __restrict__ sc) {
  if (is_f32(xdet) != WANT) return;
  int wv = threadIdx.x >> 6, lane = threadIdx.x & 63;
  long r = (long)blockIdx.x * 4 + wv;
  long i = r * 64 + lane;
  int h = (int)(r >> 11);
  float ov = (float)o[i];
  float ms = wavesum(ov * ov) * (1.f / 64.f);
  float s = rsqrtf(ms + 1e-6f);
  o[i] = (bf16)(ov * s * (float)arms[h * 64 + lane] * (float)sc[i]);
}

// ---------------- router: fp32 LN inside, logits, top-4 ---------------------
template <typename T, int WANT>
__global__ __launch_bounds__(256) void router_k(const unsigned short* __restrict__ xdet,
                                                const float* __restrict__ x2,
                                                const T* __restrict__ lnw,
                                                const T* __restrict__ lnb,
                                                const T* __restrict__ rdw,
                                                const T* __restrict__ ruw,
                                                int* __restrict__ eidx,
                                                float* __restrict__ ew,
                                                int* __restrict__ counts) {
  if (is_f32(xdet) != WANT) return;
  __shared__ float sx[4][512];
  __shared__ float st[4][64];
  __shared__ float sl[4][32];
  int wv = threadIdx.x >> 6, lane = threadIdx.x & 63;
  long t = (long)blockIdx.x * 4 + wv;
  float v[8];
  float s1 = 0.f;
#pragma unroll
  for (int j = 0; j < 8; ++j) { v[j] = x2[t * 512 + lane * 8 + j]; s1 += v[j]; }
  float mean = wavesum(s1) * (1.f / 512.f);
  float s2 = 0.f;
#pragma unroll
  for (int j = 0; j < 8; ++j) { float d = v[j] - mean; s2 += d * d; }
  float rv = rsqrtf(wavesum(s2) * (1.f / 512.f) + 1e-5f);
#pragma unroll
  for (int j = 0; j < 8; ++j)
    sx[wv][lane * 8 + j] = (v[j] - mean) * rv * (float)lnw[lane * 8 + j] + (float)lnb[lane * 8 + j];
  __syncthreads();
  float acc = 0.f;
  for (int d = 0; d < 512; ++d) acc += sx[wv][d] * (float)rdw[d * 64 + lane];
  st[wv][lane] = acc;
  __syncthreads();
  if (lane < 32) {
    float lg = 0.f;
    for (int r = 0; r < 64; ++r) lg += st[wv][r] * (float)ruw[r * 32 + lane];
    sl[wv][lane] = lg;
  }
  __syncthreads();
  if (lane == 0) {
    float vv[32];
#pragma unroll
    for (int e = 0; e < 32; ++e) vv[e] = sl[wv][e];
    int idx[4]; float tv[4];
#pragma unroll
    for (int k = 0; k < 4; ++k) {
      float best = -1e30f; int bi = 0;
      for (int e = 0; e < 32; ++e)
        if (vv[e] > best) { best = vv[e]; bi = e; }
      tv[k] = best; idx[k] = bi; vv[bi] = -1e30f;
    }
    float m = tv[0], s = 0.f, w[4];
#pragma unroll
    for (int k = 0; k < 4; ++k) { w[k] = expf(tv[k] - m); s += w[k]; }
    float inv = 1.f / s;
#pragma unroll
    for (int k = 0; k < 4; ++k) {
      eidx[t * 4 + k] = idx[k];
      ew[t * 4 + k] = w[k] * inv;
      atomicAdd(&counts[idx[k]], 1);
    }
  }
}

// ---------------- binning kernels -------------------------------------------
__global__ void offsets_k(const int* __restrict__ counts, int* __restrict__ segOff,
                          int* __restrict__ tileExp, int* __restrict__ tileStart) {
  if (threadIdx.x != 0) return;
  int off = 0, ti = 0;
  for (int e = 0; e < Ee; ++e) {
    segOff[e] = off;
    int pc = (counts[e] + 63) & ~63;
    for (int i = 0; i < pc / 64; ++i) { tileExp[ti] = e; tileStart[ti] = off + i * 64; ++ti; }
    off += pc;
  }
  for (; ti < 192; ++ti) tileExp[ti] = -1;
}
__global__ void scatter_k(const int* __restrict__ eidx, const float* __restrict__ ew,
                          const int* __restrict__ segOff, int* __restrict__ cursor,
                          int* __restrict__ slotTok, float* __restrict__ slotW) {
  int t = blockIdx.x * 256 + threadIdx.x;
#pragma unroll
  for (int k = 0; k < 4; ++k) {
    int e = eidx[t * 4 + k];
    int pos = atomicAdd(&cursor[e], 1);
    int s = segOff[e] + pos;
    slotTok[s] = t;
    slotW[s] = ew[t * 4 + k];
  }
}
__global__ void pad_k(const int* __restrict__ counts, const int* __restrict__ segOff,
                      int* __restrict__ slotTok, float* __restrict__ slotW) {
  int e = blockIdx.x;
  int c = counts[e], pc = (c + 63) & ~63;
  for (int i = c + threadIdx.x; i < pc; i += 64) {
    int s = segOff[e] + i;
    slotTok[s] = 0;
    slotW[s] = 0.f;
  }
}

// ---------------- misc ----------------
__global__ void zero_k(float* __restrict__ p, long n) {
  long i = (long)blockIdx.x * blockDim.x + threadIdx.x;
  long st = (long)gridDim.x * blockDim.x;
  for (; i < n; i += st) p[i] = 0.f;
}
template <typename TW, typename TO, int WANT>
__global__ __launch_bounds__(256) void final_k(const unsigned short* __restrict__ xdet,
                                               const float* __restrict__ x2,
                                               const TW* __restrict__ lnw,
                                               const TW* __restrict__ lnb,
                                               const float* __restrict__ acc,
                                               TO* __restrict__ out) {
  if (is_f32(xdet) != WANT) return;
  __shared__ float sm[4];
  long base = (long)blockIdx.x * 512;
  int tid = threadIdx.x;
  float x0 = x2[base + tid], x1 = x2[base + 256 + tid];
  float mean = blocksum(x0 + x1, sm) * (1.f / 512.f);
  float d0 = x0 - mean, d1 = x1 - mean;
  float var = blocksum(d0 * d0 + d1 * d1, sm) * (1.f / 512.f);
  float r = rsqrtf(var + 1e-5f);
  float f0 = d0 * r * (float)lnw[tid] + (float)lnb[tid];
  float f1 = d1 * r * (float)lnw[256 + tid] + (float)lnb[256 + tid];
  out[base + tid] = (TO)(x0 + f0 + acc[base + tid]);
  out[base + 256 + tid] = (TO)(x1 + f1 + acc[base + 256 + tid]);
}
template <typename TO, int WANT>
__global__ void loss_k(const unsigned short* __restrict__ xdet,
                       const int* __restrict__ counts, TO* __restrict__ out) {
  if (is_f32(xdet) != WANT) return;
  int lane = threadIdx.x;
  float c = lane < 32 ? (float)counts[lane] : 0.f;
  float mean = wavesum(c) * (1.f / 32.f);
  float d = lane < 32 ? (c - mean) * (c - mean) : 0.f;
  float var = wavesum(d) * (1.f / 31.f);
  if (lane == 0) out[(long)Tt * 512] = (TO)var;
}

// ---------------- host-side dual-dispatch helper for gemm_k -----------------
template <int ACT, int DUAL, int OUTBF, int ACCUM, int RESID, int ASCALE>
static inline void G(dim3 grid, hipStream_t st, const unsigned short* xdet,
                     const bf16* A, long aB, int lda,
                     const void* ascale, long asOff, long asB,
                     const void* B0, long b0Off, const void* B1, long b1Off,
                     long bB, int bK,
                     const void* bias, int biasB,
                     void* C, long cB, int ldc,
                     const void* resid, int resLd,
                     int N, int K, float scale) {
  gemm_k<float, 1, ACT, DUAL, OUTBF, ACCUM, RESID, ASCALE><<<grid, 256, 0, st>>>(
      xdet, A, aB, lda,
      ascale ? (const float*)ascale + asOff : nullptr, asB,
      (const float*)B0 + b0Off, B1 ? (const float*)B1 + b1Off : nullptr, bB, bK,
      bias ? (const float*)bias : nullptr, biasB, C, cB, ldc,
      resid ? (const float*)resid : nullptr, resLd, N, K, scale);
  gemm_k<bf16, 0, ACT, DUAL, OUTBF, ACCUM, RESID, ASCALE><<<grid, 256, 0, st>>>(
      xdet, A, aB, lda,
      ascale ? (const bf16*)ascale + asOff : nullptr, asB,
      (const bf16*)B0 + b0Off, B1 ? (const bf16*)B1 + b1Off : nullptr, bB, bK,
      bias ? (const bf16*)bias : nullptr, biasB, C, cB, ldc,
      resid ? (const bf16*)resid : nullptr, resLd, N, K, scale);
}

// ---------------------------------------------------------------------------
extern "C" void kernel_launch(void* const* d_in, const int* in_sizes, int n_in,
                              void* d_out, int out_size, void* d_ws, size_t ws_size,
                              hipStream_t stream) {
  (void)in_sizes; (void)n_in; (void)out_size;
  const void* x    = d_in[0];
  const void* ln1w = d_in[1];
  const void* ln1b = d_in[2];
  const void* ln2w = d_in[3];
  const void* ln2b = d_in[4];
  const void* q_w  = d_in[5];
  const void* q_b  = d_in[6];
  const void* k_w  = d_in[7];
  const void* k_b  = d_in[8];
  const void* v_w  = d_in[9];
  const void* v_b  = d_in[10];
  const void* aw1  = d_in[11];
  const void* ab1  = d_in[12];
  const void* aw2  = d_in[13];
  const void* ab2  = d_in[14];
  const void* bw   = d_in[15];
  const void* bbv  = d_in[16];
  const void* scw1 = d_in[17];
  const void* scb1 = d_in[18];
  const void* scw2 = d_in[19];
  const void* scb2 = d_in[20];
  const void* arms = d_in[21];
  const void* l1w  = d_in[22];
  const void* l1b  = d_in[23];
  const void* outw = d_in[24];
  const void* outb = d_in[25];
  const void* shrms= d_in[26];
  const void* shw1 = d_in[27];
  const void* shw2 = d_in[28];
  const void* shw3 = d_in[29];
  const void* rw1  = d_in[30];
  const void* rw2  = d_in[31];
  const void* rw3  = d_in[32];
  const void* rdw  = d_in[33];
  const void* ruw  = d_in[34];
  const unsigned short* xdet = (const unsigned short*)x;

  // ---- workspace map (identical to r7). Base 16 MiB; hid grows with ws_size.
  constexpr size_t MB = 1u << 20;
  char* base = (char*)d_ws;
  bf16* xn    = (bf16*)(base + 0 * MB);
  bf16* qh    = (bf16*)(base + 2 * MB);
  bf16* kh    = (bf16*)(base + 4 * MB);
  bf16* vh    = (bf16*)(base + 6 * MB);
  bf16* beta  = (bf16*)(base + 8 * MB);
  bf16* ah    = (bf16*)(base + 10 * MB);
  bf16* alpha = (bf16*)(base + 12 * MB);
  bf16* sch   = (bf16*)(base + 8 * MB);
  bf16* shct  = (bf16*)(base + 14 * MB);
  bf16* oatt  = (bf16*)(base + 8 * MB);
  bf16* conc  = (bf16*)(base + 2 * MB);
  float* x2   = (float*)(base + 4 * MB);
  bf16* xfb   = (bf16*)(base + 0 * MB);
  bf16* rbb   = (bf16*)(base + 2 * MB);
  float* acc  = (float*)(base + 12 * MB);
  int*   hcnt = (int*)(base + 8 * MB);
  int*   hcur = hcnt + 32;
  int*   hseg = hcnt + 64;
  int*   hte  = hcnt + 96;
  int*   hts  = hcnt + 288;
  int*   heidx= hcnt + 512;
  float* hew  = (float*)(hcnt + 512 + 8192);
  int*   hstok= hcnt + 512 + 16384;
  float* hsw  = (float*)(hcnt + 512 + 16384 + 10240);
  bf16* hid; long hidElems;
  if (ws_size >= 20 * MB) {
    hid = (bf16*)(base + 16 * MB);
    hidElems = (long)(ws_size - 16 * MB) / 2;
  } else {
    hid = (bf16*)(base + 8 * MB + 256 * 1024);
    hidElems = (long)(4 * MB - 256 * 1024) / 2;
  }
  int PsR = (int)((hidElems / SLOTCAP / 32) * 32);
  if (PsR > F2f) PsR = F2f;
  if (PsR < 32) PsR = 32;
  int PsS, zBsh;
  if (hidElems >= (long)Tt * F3f) {
    PsS = F3f;
    zBsh = (int)(hidElems / ((long)Tt * F3f)); if (zBsh > NSs) zBsh = NSs;
  } else {
    PsS = (int)((hidElems / Tt / 32) * 32); if (PsS > F3f) PsS = F3f;
    zBsh = 1;
  }

  // ---- attention sublayer ----
  ln_k<float, float, 1><<<Tt, 256, 0, stream>>>(xdet, (const float*)x, (const float*)ln1w, (const float*)ln1b, xn, 1e-5f);
  ln_k<bf16, bf16, 0><<<Tt, 256, 0, stream>>>(xdet, (const bf16*)x, (const bf16*)ln1w, (const bf16*)ln1b, xn, 1e-5f);

  G<1,0,1,0,0,0>(dim3(32,1,8), stream, xdet, xn,0,512, nullptr,0,0, q_w,0,nullptr,0,(long)512*64,64, q_b,64, qh,(long)Tt*64,64, nullptr,0, 64,512,1.f);
  G<1,0,1,0,0,0>(dim3(32,1,8), stream, xdet, xn,0,512, nullptr,0,0, k_w,0,nullptr,0,(long)512*64,64, k_b,64, kh,(long)Tt*64,64, nullptr,0, 64,512,1.f);
  G<1,0,1,0,0,0>(dim3(32,1,8), stream, xdet, xn,0,512, nullptr,0,0, v_w,0,nullptr,0,(long)512*64,64, v_b,64, vh,(long)Tt*64,64, nullptr,0, 64,512,1.f);
  G<2,0,1,0,0,0>(dim3(32,1,8), stream, xdet, xn,0,512, nullptr,0,0, bw,0,nullptr,0,(long)512*64,64, bbv,64, beta,(long)Tt*64,64, nullptr,0, 64,512,1.f);
  G<0,0,1,0,0,0>(dim3(32,1,8), stream, xdet, xn,0,512, nullptr,0,0, aw1,0,nullptr,0,(long)512*32,32, ab1,32, ah,(long)Tt*32,32, nullptr,0, 32,512,1.f);
  G<2,0,1,0,0,0>(dim3(32,1,8), stream, xdet, ah,(long)Tt*32,32, nullptr,0,0, aw2,0,nullptr,0,(long)32*64,64, ab2,64, alpha,(long)Tt*64,64, nullptr,0, 64,32,1.f);

  postproj_k<<<NHh * Tt / 4, 256, 0, stream>>>(qh, kh, vh, alpha, beta);

  G<0,0,1,0,0,0>(dim3(32,1,8), stream, xdet, xn,0,512, nullptr,0,0, scw1,0,nullptr,0,(long)512*32,32, scb1,32, sch,(long)Tt*32,32, nullptr,0, 32,512,1.f);
  G<2,0,1,0,0,0>(dim3(32,1,8), stream, xdet, sch,(long)Tt*32,32, nullptr,0,0, scw2,0,nullptr,0,(long)32*64,64, scb2,64, shct,(long)Tt*64,64, nullptr,0, 64,32,1.f);

  attn_k<<<dim3(16, 16), 256, 0, stream>>>(qh, kh, vh, oatt);

  orms_k<float, 1><<<NHh * Tt / 4, 256, 0, stream>>>(xdet, oatt, (const float*)arms, shct);
  orms_k<bf16, 0><<<NHh * Tt / 4, 256, 0, stream>>>(xdet, oatt, (const bf16*)arms, shct);

  G<0,0,1,0,0,0>(dim3(32,1,8), stream, xdet, oatt,(long)Tt*64,64, nullptr,0,0, l1w,0,nullptr,0,(long)64*64,64, l1b,64, conc,64,512, nullptr,0, 64,64,1.f);
  G<0,0,0,0,1,0>(dim3(32,8,1), stream, xdet, conc,0,512, nullptr,0,0, outw,0,nullptr,0,0,512, outb,0, x2,0,512, x,512, 512,512,1.f);

  // ---- MoE sublayer ----
  ln_k<float, float, 1><<<Tt, 256, 0, stream>>>(xdet, x2, (const float*)ln2w, (const float*)ln2b, xfb, 1e-5f);
  ln_k<float, bf16, 0><<<Tt, 256, 0, stream>>>(xdet, x2, (const bf16*)ln2w, (const bf16*)ln2b, xfb, 1e-5f);
  rms_k<<<Tt, 256, 0, stream>>>(xfb, rbb);
  zero_k<<<256, 256, 0, stream>>>(acc, (long)Tt * 512);
  zero_k<<<1, 64, 0, stream>>>((float*)hcnt, 64);
  router_k<float, 1><<<Tt / 4, 256, 0, stream>>>(xdet, x2, (const float*)ln2w, (const float*)ln2b, (const float*)rdw, (const float*)ruw, heidx, hew, hcnt);
  router_k<bf16, 0><<<Tt / 4, 256, 0, stream>>>(xdet, x2, (const bf16*)ln2w, (const bf16*)ln2b, (const bf16*)rdw, (const bf16*)ruw, heidx, hew, hcnt);
  offsets_k<<<1, 64, 0, stream>>>(hcnt, hseg, hte, hts);
  scatter_k<<<Tt / 256, 256, 0, stream>>>(heidx, hew, hseg, hcur, hstok, hsw);
  pad_k<<<Ee, 64, 0, stream>>>(hcnt, hseg, hstok, hsw);

  // shared experts: SwiGLU (ascale = rmsnorm weight fold) then w2 @ 1/8
  for (int n0e = 0; n0e < NSs; n0e += zBsh) {
    int zc = NSs - n0e < zBsh ? NSs - n0e : zBsh;
    for (int off = 0; off < F3f; off += PsS) {
      int Np = F3f - off < PsS ? F3f - off : PsS;
      G<0,1,1,0,0,1>(dim3(32,(Np+63)/64,zc), stream, xdet, rbb,0,512,
                     shrms,(long)n0e*512,512,
                     shw1,(long)n0e*512*F3f + off, shw3,(long)n0e*512*F3f + off,
                     (long)512*F3f, F3f,
                     nullptr,0, hid,(long)Tt*PsS,PsS, nullptr,0, Np,512,1.f);
      G<0,0,0,1,0,0>(dim3(32,8,zc), stream, xdet, hid,(long)Tt*PsS,PsS, nullptr,0,0,
                     shw2,(long)n0e*F3f*512 + (long)off*512, nullptr,0,
                     (long)F3f*512, 512,
                     nullptr,0, acc,0,512, nullptr,0, 512,Np,0.125f);
    }
  }

  // routed experts: sparse token-gathered, scatter-add with routing weight
  for (int off = 0; off < F2f; off += PsR) {
    int Np = F2f - off < PsR ? F2f - off : PsR;
    dim3 g1(MAXTILE, (Np + 63) / 64);
    moe1_k<float, 1><<<g1, 256, 0, stream>>>(xdet, hte, hts, hstok, xfb, (const float*)rw1, (const float*)rw3, hid, PsR, off, Np);
    moe1_k<bf16, 0><<<g1, 256, 0, stream>>>(xdet, hte, hts, hstok, xfb, (const bf16*)rw1, (const bf16*)rw3, hid, PsR, off, Np);
    dim3 g2(MAXTILE, 8);
    moe2_k<float, 1><<<g2, 256, 0, stream>>>(xdet, hte, hts, hstok, hsw, hid, PsR, off, Np, (const float*)rw2, acc);
    moe2_k<bf16, 0><<<g2, 256, 0, stream>>>(xdet, hte, hts, hstok, hsw, hid, PsR, off, Np, (const bf16*)rw2, acc);
  }

  final_k<float, float, 1><<<Tt, 256, 0, stream>>>(xdet, x2, (const float*)ln2w, (const float*)ln2b, acc, (float*)d_out);
  final_k<bf16, bf16, 0><<<Tt, 256, 0, stream>>>(xdet, x2, (const bf16*)ln2w, (const bf16*)ln2b, acc, (bf16*)d_out);
  loss_k<float, 1><<<1, 64, 0, stream>>>(xdet, hcnt, (float*)d_out);
  loss_k<bf16, 0><<<1, 64, 0, stream>>>(xdet, hcnt, (bf16*)d_out);
}